// Round 6
// baseline (531.781 us; speedup 1.0000x reference)
//
#include <hip/hip_runtime.h>

// ---------- problem constants ----------
#define BATCH   32768
#define SEQLEN  12
#define EMB     64
#define H       128
#define MLP     1024
#define Z       32
#define ZX      1056      // MLP + Z
#define KP      1088      // ZX padded to 17*64 (big path)
#define NG      512       // 4*H gates

typedef _Float16 f16x8 __attribute__((ext_vector_type(8)));
typedef float    f32x4 __attribute__((ext_vector_type(4)));

// ---------- workspace layouts ----------
// small path (ws < 217,651,200): round-3 layout, total 146,249,728
#define S_WCAT_OFF   0u
#define S_W2H_OFF    3244032u
#define S_WHHF_OFF   3506176u
#define S_WC_OFF     3637248u
#define S_BIAS2_OFF  3641344u
#define S_T1_OFF     3643392u
#define S_GP_OFF     70752256u
#define S_H0_OFF     137861120u
// big path: wcat stride 1088 + zx16 buffer, total 217,651,200
#define B_WCAT_OFF   0u           // 1536*1088*2 = 3,342,336
#define B_W2H_OFF    3342336u
#define B_WHHF_OFF   3604480u
#define B_WC_OFF     3735552u
#define B_BIAS2_OFF  3739648u
#define B_T1_OFF     3741696u
#define B_GP_OFF     70850560u
#define B_H0_OFF     137959424u
#define B_ZX16_OFF   146348032u
#define B_TOTAL      217651200ull

__device__ __forceinline__ float sigf(float x) {
    return __builtin_amdgcn_rcpf(1.0f + __expf(-x));
}
__device__ __forceinline__ float tanhfast(float x) {
    return 2.0f * __builtin_amdgcn_rcpf(1.0f + __expf(-2.0f * x)) - 1.0f;
}

// async global->LDS, 16B per lane. LDS dest = wave-uniform base + lane*16.
__device__ __forceinline__ void gload16(const void* g, void* l) {
    __builtin_amdgcn_global_load_lds(
        (const __attribute__((address_space(1))) unsigned int*)(unsigned long long)(uintptr_t)g,
        (__attribute__((address_space(3))) unsigned int*)(unsigned int)(uintptr_t)l,
        16, 0, 0);
}

// ---------------------------------------------------------------------------
// prep: pack weights fp16 (wcat stride = cs, zero-padded past 1056),
// fold biases, fold rel_pos feedback into W_hh.
// ---------------------------------------------------------------------------
__global__ __launch_bounds__(256) void prep_kernel(
    const float* __restrict__ W_ih, const float* __restrict__ W_hh_in,
    const float* __restrict__ b_ih, const float* __restrict__ b_hh,
    const float* __restrict__ W1,   const float* __restrict__ W2,
    const float* __restrict__ W_sp, const float* __restrict__ b_sp,
    const float* __restrict__ W_hp, int cs,
    _Float16* __restrict__ wcat, _Float16* __restrict__ w2h,
    _Float16* __restrict__ whhf, float* __restrict__ wc, float* __restrict__ bias2)
{
    const int bid = blockIdx.x;
    const int tid = threadIdx.x;
    if (bid < 1536) {
        const float* src = (bid < 1024) ? (W1 + (size_t)bid * ZX)
                                        : (W_ih + (size_t)(bid - 1024) * 1120);
        _Float16* dst = wcat + (size_t)bid * cs;
        for (int k = tid; k < cs; k += 256)
            dst[k] = (k < ZX) ? (_Float16)src[k] : (_Float16)0.f;
    } else if (bid < 1664) {
        const int n = bid - 1536;
        for (int k = tid; k < MLP; k += 256)
            w2h[n * MLP + k] = (_Float16)W2[n * MLP + k];
    } else if (bid < 1920) {
        const int n = (bid - 1664) * 2 + (tid >> 7);
        const int k = tid & 127;
        float wc0 = 0.f, wc1 = 0.f;
        for (int e = 0; e < EMB; ++e) {
            const float we = W_ih[(size_t)n * 1120 + ZX + e];
            wc0 += we * W_sp[e * 2];
            wc1 += we * W_sp[e * 2 + 1];
        }
        whhf[n * H + k] = (_Float16)(W_hh_in[n * H + k] + wc0 * W_hp[k] + wc1 * W_hp[H + k]);
    } else {
        const int t = (bid - 1920) * 256 + tid;
        if (t < 1024) {
            const int n = t >> 1, j = t & 1;
            float s = 0.f;
            for (int e = 0; e < EMB; ++e)
                s += W_ih[(size_t)n * 1120 + ZX + e] * W_sp[e * 2 + j];
            wc[t] = s;
        } else if (t < 1536) {
            const int n = t - 1024;
            float s = b_ih[n] + b_hh[n];
            for (int e = 0; e < EMB; ++e)
                s += W_ih[(size_t)n * 1120 + ZX + e] * b_sp[e];
            bias2[n] = s;
        }
    }
}

// ---------------------------------------------------------------------------
// zxcast (big path): zx16[32768][1088] = fp16([enc | z | zeros])
// 8 halfs per thread; grid = 4456448/256 = 17408 blocks.
// ---------------------------------------------------------------------------
__global__ __launch_bounds__(256) void zxcast_kernel(
    const float* __restrict__ enc, const float* __restrict__ zin,
    _Float16* __restrict__ zx16)
{
    const int gid = blockIdx.x * 256 + threadIdx.x;
    if (gid < 4194304) {                       // enc: 128 chunks/row
        const int row = gid >> 7, cw = gid & 127;
        const float4* s = (const float4*)(enc + (size_t)row * MLP + cw * 8);
        const float4 f0 = s[0], f1 = s[1];
        f16x8 v = {(_Float16)f0.x, (_Float16)f0.y, (_Float16)f0.z, (_Float16)f0.w,
                   (_Float16)f1.x, (_Float16)f1.y, (_Float16)f1.z, (_Float16)f1.w};
        *(f16x8*)(zx16 + (size_t)row * KP + cw * 8) = v;
    } else if (gid < 4325376) {                // z: 4 chunks/row
        const int g2 = gid - 4194304;
        const int row = g2 >> 2, cw = g2 & 3;
        const float4* s = (const float4*)(zin + (size_t)row * Z + cw * 8);
        const float4 f0 = s[0], f1 = s[1];
        f16x8 v = {(_Float16)f0.x, (_Float16)f0.y, (_Float16)f0.z, (_Float16)f0.w,
                   (_Float16)f1.x, (_Float16)f1.y, (_Float16)f1.z, (_Float16)f1.w};
        *(f16x8*)(zx16 + (size_t)row * KP + MLP + cw * 8) = v;
    } else {                                   // pad: 4 chunks/row of zeros
        const int g2 = gid - 4325376;
        const int row = g2 >> 2, cw = g2 & 3;
        f16x8 v = {};
        *(f16x8*)(zx16 + (size_t)row * KP + ZX + cw * 8) = v;
    }
}

// ---------------------------------------------------------------------------
// GEMM1 big path, round 5: 256x256 tile, BK=64, 512 thr (8 waves, 2M x 4N),
// 128 KB double-buffered LDS, 4-phase-per-K-tile schedule with counted
// vmcnt (T3+T4) + s_setprio around MFMA clusters (T5). Verified round 1.
// ---------------------------------------------------------------------------
__global__ __launch_bounds__(512, 2) void gemm1_big_kernel(
    const _Float16* __restrict__ zx16, const _Float16* __restrict__ wcat,
    const float* __restrict__ bias1, const float* __restrict__ bias2g,
    _Float16* __restrict__ t1, float* __restrict__ gperm)
{
    __shared__ _Float16 s_a[2][256 * 64];   // 64 KB
    __shared__ _Float16 s_b[2][256 * 64];   // 64 KB

    const int tid = threadIdx.x;
    const int b   = blockIdx.x;
    const int swz = (b & 7) * 96 + (b >> 3);
    const int mt  = swz / 6, nt = swz % 6;
    const int m0  = mt * 256, n0 = nt * 256;

    const int lane = tid & 63, wv = tid >> 6;
    const int wm   = wv >> 2,  wn = wv & 3;
    const int l15  = lane & 15, q = lane >> 4;

    const int rowS = tid >> 3;
    const int chS  = (tid & 7) ^ (rowS & 7);

    const _Float16* gA = zx16 + (size_t)(m0 + rowS) * KP + chS * 8;
    const _Float16* gB = wcat + (size_t)(n0 + rowS) * KP + chS * 8;
    const size_t rstep = (size_t)64 * KP;

    const int ph0  = q ^ (l15 & 7);           // k-slice 0
    const int ph1  = (4 + q) ^ (l15 & 7);     // k-slice 1
    const int aof0 = (wm * 128 + l15) * 64 + ph0 * 8;
    const int aof1 = (wm * 128 + l15) * 64 + ph1 * 8;
    const int bof0 = (wn * 64 + l15) * 64 + ph0 * 8;
    const int bof1 = (wn * 64 + l15) * 64 + ph1 * 8;

    f32x4 acc[8][4] = {};

    // prologue: stage K-tile 0 into buffer 0 (8 loads)
    {
        _Float16* dA = &s_a[0][0] + wv * 512;
        _Float16* dB = &s_b[0][0] + wv * 512;
        #pragma unroll
        for (int j = 0; j < 4; ++j) gload16(gA + j * rstep, dA + j * 4096);
        #pragma unroll
        for (int j = 0; j < 4; ++j) gload16(gB + j * rstep, dB + j * 4096);
    }

    #pragma unroll 2
    for (int kt = 0; kt < 16; ++kt) {
        const int cur = kt & 1;
        const _Float16* sA = &s_a[cur][0];
        const _Float16* sB = &s_b[cur][0];
        _Float16* dA = &s_a[cur ^ 1][0] + wv * 512;
        _Float16* dB = &s_b[cur ^ 1][0] + wv * 512;
        const _Float16* gA1 = gA + (kt + 1) * 64;
        const _Float16* gB1 = gB + (kt + 1) * 64;

        f16x8 af[4], bf[4];

        // ---- PH0: ks0/qm0; stage A-half0 of t+1; counted wait for tile t
        gload16(gA1,         dA);
        gload16(gA1 + rstep, dA + 4096);
        asm volatile("s_waitcnt vmcnt(2)\n\ts_barrier" ::: "memory");
        #pragma unroll
        for (int i = 0; i < 4; ++i) af[i] = *(const f16x8*)(sA + aof0 + i * 1024);
        #pragma unroll
        for (int i = 0; i < 4; ++i) bf[i] = *(const f16x8*)(sB + bof0 + i * 1024);
        __builtin_amdgcn_s_setprio(1);
        #pragma unroll
        for (int n_ = 0; n_ < 4; ++n_)
            #pragma unroll
            for (int m_ = 0; m_ < 4; ++m_)
                acc[m_][n_] = __builtin_amdgcn_mfma_f32_16x16x32_f16(af[m_], bf[n_], acc[m_][n_], 0, 0, 0);
        __builtin_amdgcn_s_setprio(0);
        asm volatile("s_barrier" ::: "memory");

        // ---- PH1: ks0/qm1; stage A-half1 of t+1 (bf ks0 reused in regs)
        gload16(gA1 + 2 * rstep, dA + 8192);
        gload16(gA1 + 3 * rstep, dA + 12288);
        #pragma unroll
        for (int i = 0; i < 4; ++i) af[i] = *(const f16x8*)(sA + aof0 + 4096 + i * 1024);
        asm volatile("s_barrier" ::: "memory");
        __builtin_amdgcn_s_setprio(1);
        #pragma unroll
        for (int n_ = 0; n_ < 4; ++n_)
            #pragma unroll
            for (int m_ = 0; m_ < 4; ++m_)
                acc[4 + m_][n_] = __builtin_amdgcn_mfma_f32_16x16x32_f16(af[m_], bf[n_], acc[4 + m_][n_], 0, 0, 0);
        __builtin_amdgcn_s_setprio(0);
        asm volatile("s_barrier" ::: "memory");

        // ---- PH2: ks1/qm0; stage B-half0 of t+1
        gload16(gB1,         dB);
        gload16(gB1 + rstep, dB + 4096);
        #pragma unroll
        for (int i = 0; i < 4; ++i) af[i] = *(const f16x8*)(sA + aof1 + i * 1024);
        #pragma unroll
        for (int i = 0; i < 4; ++i) bf[i] = *(const f16x8*)(sB + bof1 + i * 1024);
        asm volatile("s_barrier" ::: "memory");
        __builtin_amdgcn_s_setprio(1);
        #pragma unroll
        for (int n_ = 0; n_ < 4; ++n_)
            #pragma unroll
            for (int m_ = 0; m_ < 4; ++m_)
                acc[m_][n_] = __builtin_amdgcn_mfma_f32_16x16x32_f16(af[m_], bf[n_], acc[m_][n_], 0, 0, 0);
        __builtin_amdgcn_s_setprio(0);
        asm volatile("s_barrier" ::: "memory");

        // ---- PH3: ks1/qm1; stage B-half1 of t+1
        gload16(gB1 + 2 * rstep, dB + 8192);
        gload16(gB1 + 3 * rstep, dB + 12288);
        #pragma unroll
        for (int i = 0; i < 4; ++i) af[i] = *(const f16x8*)(sA + aof1 + 4096 + i * 1024);
        asm volatile("s_barrier" ::: "memory");
        __builtin_amdgcn_s_setprio(1);
        #pragma unroll
        for (int n_ = 0; n_ < 4; ++n_)
            #pragma unroll
            for (int m_ = 0; m_ < 4; ++m_)
                acc[4 + m_][n_] = __builtin_amdgcn_mfma_f32_16x16x32_f16(af[m_], bf[n_], acc[4 + m_][n_], 0, 0, 0);
        __builtin_amdgcn_s_setprio(0);
        asm volatile("s_barrier" ::: "memory");
    }

    // ---- tail: K-tile 16 (buffer 0), full drain allowed (no more stages)
    {
        const _Float16* sA = &s_a[0][0];
        const _Float16* sB = &s_b[0][0];
        asm volatile("s_waitcnt vmcnt(0)\n\ts_barrier" ::: "memory");
        f16x8 af[4], bf[4];
        #pragma unroll
        for (int i = 0; i < 4; ++i) af[i] = *(const f16x8*)(sA + aof0 + i * 1024);
        #pragma unroll
        for (int i = 0; i < 4; ++i) bf[i] = *(const f16x8*)(sB + bof0 + i * 1024);
        __builtin_amdgcn_s_setprio(1);
        #pragma unroll
        for (int n_ = 0; n_ < 4; ++n_)
            #pragma unroll
            for (int m_ = 0; m_ < 4; ++m_)
                acc[m_][n_] = __builtin_amdgcn_mfma_f32_16x16x32_f16(af[m_], bf[n_], acc[m_][n_], 0, 0, 0);
        #pragma unroll
        for (int i = 0; i < 4; ++i) af[i] = *(const f16x8*)(sA + aof0 + 4096 + i * 1024);
        #pragma unroll
        for (int n_ = 0; n_ < 4; ++n_)
            #pragma unroll
            for (int m_ = 0; m_ < 4; ++m_)
                acc[4 + m_][n_] = __builtin_amdgcn_mfma_f32_16x16x32_f16(af[m_], bf[n_], acc[4 + m_][n_], 0, 0, 0);
        #pragma unroll
        for (int i = 0; i < 4; ++i) af[i] = *(const f16x8*)(sA + aof1 + i * 1024);
        #pragma unroll
        for (int i = 0; i < 4; ++i) bf[i] = *(const f16x8*)(sB + bof1 + i * 1024);
        #pragma unroll
        for (int n_ = 0; n_ < 4; ++n_)
            #pragma unroll
            for (int m_ = 0; m_ < 4; ++m_)
                acc[m_][n_] = __builtin_amdgcn_mfma_f32_16x16x32_f16(af[m_], bf[n_], acc[m_][n_], 0, 0, 0);
        #pragma unroll
        for (int i = 0; i < 4; ++i) af[i] = *(const f16x8*)(sA + aof1 + 4096 + i * 1024);
        #pragma unroll
        for (int n_ = 0; n_ < 4; ++n_)
            #pragma unroll
            for (int m_ = 0; m_ < 4; ++m_)
                acc[4 + m_][n_] = __builtin_amdgcn_mfma_f32_16x16x32_f16(af[m_], bf[n_], acc[4 + m_][n_], 0, 0, 0);
        __builtin_amdgcn_s_setprio(0);
    }

    // ---- epilogue: nt<4 -> t1 (relu, fp16); nt>=4 -> gperm (fp32, permuted)
    if (nt < 4) {
        #pragma unroll
        for (int im = 0; im < 8; ++im)
            #pragma unroll
            for (int in_ = 0; in_ < 4; ++in_) {
                const int n = n0 + wn * 64 + in_ * 16 + l15;
                const float bb = bias1[n];
                const int mbase = m0 + wm * 128 + im * 16 + q * 4;
                #pragma unroll
                for (int r = 0; r < 4; ++r) {
                    float v = acc[im][in_][r] + bb;
                    v = v > 0.f ? v : 0.f;
                    t1[(size_t)(mbase + r) * MLP + n] = (_Float16)v;
                }
            }
    } else {
        #pragma unroll
        for (int im = 0; im < 8; ++im)
            #pragma unroll
            for (int in_ = 0; in_ < 4; ++in_) {
                const int n = (n0 - 1024) + wn * 64 + in_ * 16 + l15;
                const float bb = bias2g[n];
                const int m4 = (m0 + wm * 128 + im * 16 + q * 4) >> 2;
                float4 v;
                v.x = acc[im][in_][0] + bb;
                v.y = acc[im][in_][1] + bb;
                v.z = acc[im][in_][2] + bb;
                v.w = acc[im][in_][3] + bb;
                *(float4*)(gperm + ((size_t)m4 * NG + n) * 4) = v;
            }
    }
}

// ---------------------------------------------------------------------------
// GEMM1 small path: round-3 kernel verbatim (fp32 A, BK=32, stride 1056).
// ---------------------------------------------------------------------------
__global__ __launch_bounds__(256) void gemm1_small_kernel(
    const float* __restrict__ enc, const float* __restrict__ zin,
    const _Float16* __restrict__ wcat,
    const float* __restrict__ bias1, const float* __restrict__ bias2g,
    _Float16* __restrict__ t1, float* __restrict__ gperm)
{
    __shared__ float    s_a[128 * 32];
    __shared__ _Float16 s_b[128 * 32];

    const int tid = threadIdx.x;
    const int b = blockIdx.x;
    const int x = b & 7, s = b >> 3;
    const int mt = x * 32 + s / 12;
    const int bn = s % 12;
    const int m0 = mt * 128;

    const int lane = tid & 63, wv = tid >> 6;
    const int wm = wv >> 1, wn = wv & 1;
    const int l15 = lane & 15, q = lane >> 4;

    const int rowA = tid >> 3;
    const int chA  = (tid & 7) ^ ((tid >> 3) & 7);
    const int rowB = tid >> 2;
    const int chB  = (tid & 3) ^ ((tid >> 3) & 3);

    const int ca0 = (2 * q) ^ (l15 & 7);
    const int cb  = q ^ ((l15 >> 1) & 3);

    f32x4 acc[4][4] = {};

    for (int kt = 0; kt < 33; ++kt) {
        const float* abase;
        size_t astride;
        if (kt < 32) { abase = enc + (size_t)m0 * MLP + kt * 32; astride = MLP; }
        else         { abase = zin + (size_t)m0 * Z;             astride = Z;   }

        __syncthreads();
        #pragma unroll
        for (int i = 0; i < 4; ++i)
            gload16(abase + (size_t)(i * 32 + rowA) * astride + chA * 4,
                    s_a + i * 1024 + wv * 256);
        #pragma unroll
        for (int i = 0; i < 2; ++i)
            gload16(wcat + (size_t)(bn * 128 + i * 64 + rowB) * ZX + kt * 32 + chB * 8,
                    s_b + i * 2048 + wv * 512);
        __syncthreads();

        f16x8 af[4];
        #pragma unroll
        for (int im = 0; im < 4; ++im) {
            const float* ap = s_a + (wm * 64 + im * 16 + l15) * 32;
            const float4 f0 = *(const float4*)(ap + ca0 * 4);
            const float4 f1 = *(const float4*)(ap + (ca0 ^ 1) * 4);
            af[im] = f16x8{(_Float16)f0.x, (_Float16)f0.y, (_Float16)f0.z, (_Float16)f0.w,
                           (_Float16)f1.x, (_Float16)f1.y, (_Float16)f1.z, (_Float16)f1.w};
        }
        #pragma unroll
        for (int in_ = 0; in_ < 4; ++in_) {
            const f16x8 bf = *(const f16x8*)(s_b + (wn * 64 + in_ * 16 + l15) * 32 + cb * 8);
            #pragma unroll
            for (int im = 0; im < 4; ++im)
                acc[im][in_] = __builtin_amdgcn_mfma_f32_16x16x32_f16(af[im], bf, acc[im][in_], 0, 0, 0);
        }
    }

    if (bn < 8) {
        #pragma unroll
        for (int im = 0; im < 4; ++im)
            #pragma unroll
            for (int in_ = 0; in_ < 4; ++in_) {
                const int n = bn * 128 + wn * 64 + in_ * 16 + l15;
                const float bb = bias1[n];
                #pragma unroll
                for (int r = 0; r < 4; ++r) {
                    const int m = m0 + wm * 64 + im * 16 + q * 4 + r;
                    float v = acc[im][in_][r] + bb;
                    v = v > 0.f ? v : 0.f;
                    t1[(size_t)m * MLP + n] = (_Float16)v;
                }
            }
    } else {
        #pragma unroll
        for (int im = 0; im < 4; ++im)
            #pragma unroll
            for (int in_ = 0; in_ < 4; ++in_) {
                const int n = (bn - 8) * 128 + wn * 64 + in_ * 16 + l15;
                const float bb = bias2g[n];
                const int m4 = (m0 + wm * 64 + im * 16 + q * 4) >> 2;
                float4 v;
                v.x = acc[im][in_][0] + bb;
                v.y = acc[im][in_][1] + bb;
                v.z = acc[im][in_][2] + bb;
                v.w = acc[im][in_][3] + bb;
                *(float4*)(gperm + ((size_t)m4 * NG + n) * 4) = v;
            }
    }
}

// ---------------------------------------------------------------------------
// GEMM2 v2: h0[32768,128] = fp16(relu(t1 @ w2h.T + b2)). Tile 64x128,
// grid 512 -> 2 blocks/CU. Wave w: n-cols w*32 (2 frags), m 0..63 (4 frags).
// 4-chunk XOR-with-parity swizzle -> 2-way banks (free).
// ---------------------------------------------------------------------------
__global__ __launch_bounds__(256) void gemm2_kernel(
    const _Float16* __restrict__ t1, const _Float16* __restrict__ w2h,
    const float* __restrict__ b2, _Float16* __restrict__ h0buf)
{
    __shared__ _Float16 s_a[64 * 32];    // 4 KB
    __shared__ _Float16 s_b[128 * 32];   // 8 KB

    const int tid = threadIdx.x;
    const int m0  = blockIdx.x * 64;
    const int lane = tid & 63, wv = tid >> 6;
    const int l15 = lane & 15, q = lane >> 4;

    // staging: slot P -> row=P>>2, pch=P&3, logical c=(pch^row^(row>>2))&3
    const int rowS = tid >> 2;
    const int chS  = ((tid & 3) ^ (tid >> 2) ^ (tid >> 4)) & 3;
    // frag phys chunk: (q ^ l15 ^ (l15>>2)) & 3
    const int phF  = (q ^ l15 ^ (l15 >> 2)) & 3;

    f32x4 acc[4][2] = {};

    for (int kt = 0; kt < 32; ++kt) {
        __syncthreads();
        gload16(t1 + (size_t)(m0 + rowS) * MLP + kt * 32 + chS * 8,
                s_a + wv * 512);
        #pragma unroll
        for (int i = 0; i < 2; ++i) {
            const int row = i * 64 + rowS;
            const int c   = ((tid & 3) ^ row ^ (row >> 2)) & 3;
            gload16(w2h + (size_t)row * MLP + kt * 32 + c * 8,
                    s_b + i * 2048 + wv * 512);
        }
        __syncthreads();

        f16x8 af[4];
        #pragma unroll
        for (int im = 0; im < 4; ++im)
            af[im] = *(const f16x8*)(s_a + (im * 16 + l15) * 32 + phF * 8);
        #pragma unroll
        for (int in_ = 0; in_ < 2; ++in_) {
            const f16x8 bf = *(const f16x8*)(s_b + (wv * 32 + in_ * 16 + l15) * 32 + phF * 8);
            #pragma unroll
            for (int im = 0; im < 4; ++im)
                acc[im][in_] = __builtin_amdgcn_mfma_f32_16x16x32_f16(af[im], bf, acc[im][in_], 0, 0, 0);
        }
    }

    #pragma unroll
    for (int im = 0; im < 4; ++im)
        #pragma unroll
        for (int in_ = 0; in_ < 2; ++in_) {
            const int n = wv * 32 + in_ * 16 + l15;
            const float bb = b2[n];
            #pragma unroll
            for (int r = 0; r < 4; ++r) {
                const int m = m0 + im * 16 + q * 4 + r;
                float v = acc[im][in_][r] + bb;
                v = v > 0.f ? v : 0.f;
                h0buf[(size_t)m * H + n] = (_Float16)v;
            }
        }
}

// ---------------------------------------------------------------------------
// Recurrence, round 10: 1024 threads = 16 waves = 4 waves/SIMD (was 2).
// Same 512-block grid, same LDS layouts (s_whh stride 136, s_h stride 136,
// s_wc, s_whp [8][36]), same algorithm and per-accumulator math order as the
// verified kernels. The m-dimension splits across wave pairs: wave
// (wg = w16&7, wm2 = w16>>3) computes gate columns wg*16+l15 for m-rows
// wm2*32 .. wm2*32+31 (2 m-frags instead of 4). Per-thread state halves
// (gb[2][4]+acc[2][4]+cst[2] = 72 VGPR core), fitting the 128-VGPR cap that
// 16 waves/CU requires (__launch_bounds__(1024,4)).
// relpos16 (16-wide partials, verified round 5): 64 rows x 2 j x 8 p = 1024
// threads exactly. Init s_p uses the 32-wide round-3 form under tid<512.
// ---------------------------------------------------------------------------
__device__ __forceinline__ float relpos16(const _Float16* s_h, const float* s_whp,
                                          int row, int j, int p) {
    const f16x8 a = *(const f16x8*)(s_h + row * 136 + p * 16);
    const f16x8 b = *(const f16x8*)(s_h + row * 136 + p * 16 + 8);
    const float* wp = s_whp + (j * 4 + (p >> 1)) * 36 + (p & 1) * 16;
    float s = 0.f;
    #pragma unroll
    for (int u = 0; u < 8; ++u)
        s += (float)a[u] * wp[u] + (float)b[u] * wp[8 + u];
    s += __shfl_down(s, 4, 64);
    s += __shfl_down(s, 2, 64);
    s += __shfl_down(s, 1, 64);
    return s;   // valid at p == 0
}

__global__ __launch_bounds__(1024, 4) void recur_kernel(
    const float* __restrict__ gperm, const _Float16* __restrict__ h0buf,
    const _Float16* __restrict__ whhf, const float* __restrict__ wc,
    const float* __restrict__ whp, const float* __restrict__ bhp,
    const float* __restrict__ lpr, float* __restrict__ out)
{
    __shared__ _Float16 s_whh[512 * 136];
    __shared__ _Float16 s_h[64 * 136];
    __shared__ float    s_p[128];
    __shared__ float    s_wc[1024];
    __shared__ float    s_whp[8 * 36];   // [j*4+part][32 floats], +4 pad
    __shared__ float    s_bhp[2];

    const int tid = threadIdx.x;
    const int m0  = blockIdx.x * 64;
    const int lane = tid & 63;
    const int w16 = tid >> 6;           // 0..15
    const int wg  = w16 & 7;            // gate-column wave index
    const int wm2 = w16 >> 3;           // m-half
    const int l15 = lane & 15, q = lane >> 4;

    // ---- staging (mechanically re-mapped to 1024 threads) ----
    #pragma unroll
    for (int i = 0; i < 8; ++i) {
        const int cid = tid + i * 1024;
        const int row = cid >> 4, ch = cid & 15;
        *(uint4*)(s_whh + row * 136 + ch * 8) = *(const uint4*)(whhf + row * H + ch * 8);
    }
    if (tid < 256) *(float4*)(s_wc + tid * 4)  = *(const float4*)(wc + tid * 4);
    if (tid < 64) {
        const int jp = tid >> 3;            // 0..7 = j*4+part
        const int e8 = tid & 7;             // 4-float chunk 0..7
        const int j = jp >> 2, part = jp & 3;
        *(float4*)(s_whp + jp * 36 + e8 * 4) = *(const float4*)(whp + j * H + part * 32 + e8 * 4);
    }
    if (tid < 2)   s_bhp[tid] = bhp[tid];
    if (tid < 128) s_p[tid] = lpr[(size_t)m0 * 2 + tid];
    {
        const int row = tid >> 4, ch = tid & 15;
        *(uint4*)(s_h + row * 136 + ch * 8) = *(const uint4*)(h0buf + (size_t)(m0 + row) * H + ch * 8);
    }

    // gate-bias fragments from gperm
    f32x4 gb[2][4];
    #pragma unroll
    for (int im = 0; im < 2; ++im) {
        const int m4 = (m0 >> 2) + wm2 * 8 + im * 4 + q;
        #pragma unroll
        for (int g = 0; g < 4; ++g) {
            const float4 v = *(const float4*)(gperm + ((size_t)m4 * NG + g * H + wg * 16 + l15) * 4);
            gb[im][g] = f32x4{v.x, v.y, v.z, v.w};
        }
    }

    f32x4 cst[2] = {};

    __syncthreads();

    // ---- init: s_p -= h0 . whp (round-3 32-wide form, tid<512) ----
    if (tid < 512) {
        const int part = tid & 3;
        const int j    = (tid >> 2) & 1;
        const int row  = tid >> 3;
        const int jp   = j * 4 + part;
        float sum = 0.f;
        #pragma unroll
        for (int u = 0; u < 4; ++u) {
            const f16x8 hv = *(const f16x8*)(s_h + row * 136 + part * 32 + u * 8);
            const float4* wp = (const float4*)(s_whp + jp * 36 + u * 8);
            const float4 w0 = wp[0], w1 = wp[1];
            sum += (float)hv[0] * w0.x + (float)hv[1] * w0.y + (float)hv[2] * w0.z + (float)hv[3] * w0.w
                 + (float)hv[4] * w1.x + (float)hv[5] * w1.y + (float)hv[6] * w1.z + (float)hv[7] * w1.w;
        }
        sum += __shfl_down(sum, 2, 64);
        sum += __shfl_down(sum, 1, 64);
        if (part == 0) s_p[row * 2 + j] -= sum;
    }
    __syncthreads();

    float wc0[4], wc1[4], cg[4];
    #pragma unroll
    for (int g = 0; g < 4; ++g) {
        const int n = g * H + wg * 16 + l15;
        wc0[g] = s_wc[n * 2];
        wc1[g] = s_wc[n * 2 + 1];
        cg[g]  = wc0[g] * s_bhp[0] + wc1[g] * s_bhp[1];
    }
    #pragma unroll
    for (int im = 0; im < 2; ++im)
        #pragma unroll
        for (int r = 0; r < 4; ++r) {
            const int mrow = wm2 * 32 + im * 16 + q * 4 + r;
            const float pa = s_p[mrow * 2], pb = s_p[mrow * 2 + 1];
            #pragma unroll
            for (int g = 0; g < 4; ++g)
                gb[im][g][r] += pa * wc0[g] + pb * wc1[g];
        }

    const int rp_p = tid & 7, rp_j = (tid >> 3) & 1, rp_r = tid >> 4;  // rows 0..63

    for (int t = 0; t < SEQLEN; ++t) {
        // ---- phase A: MFMA gates(t) from s_h(t-1); rel-pos(t-1) hidden ----
        f32x4 acc[2][4];
        #pragma unroll
        for (int kt = 0; kt < 4; ++kt) {
            f16x8 af[2];
            #pragma unroll
            for (int im = 0; im < 2; ++im)
                af[im] = *(const f16x8*)(s_h + (wm2 * 32 + im * 16 + l15) * 136 + kt * 32 + q * 8);
            #pragma unroll
            for (int g = 0; g < 4; ++g) {
                const f16x8 bf = *(const f16x8*)(s_whh + (g * H + wg * 16 + l15) * 136 + kt * 32 + q * 8);
                #pragma unroll
                for (int im = 0; im < 2; ++im)
                    acc[im][g] = __builtin_amdgcn_mfma_f32_16x16x32_f16(
                        af[im], bf, (kt == 0) ? gb[im][g] : acc[im][g], 0, 0, 0);
            }
        }
        if (t > 0) {
            const float sm = relpos16(s_h, s_whp, rp_r, rp_j, rp_p);
            if (rp_p == 0)
                out[(size_t)(t - 1) * (BATCH * 2) + (size_t)(m0 + rp_r) * 2 + rp_j]
                    = sm + s_bhp[rp_j];
        } else {
            #pragma unroll
            for (int im = 0; im < 2; ++im)
                #pragma unroll
                for (int r = 0; r < 4; ++r) {
                    const int mrow = wm2 * 32 + im * 16 + q * 4 + r;
                    const float pa = s_p[mrow * 2], pb = s_p[mrow * 2 + 1];
                    #pragma unroll
                    for (int g = 0; g < 4; ++g)
                        gb[im][g][r] += cg[g] - (pa * wc0[g] + pb * wc1[g]);
                }
        }
        __syncthreads();

        // ---- phase B: LSTM cell update, write s_h(t) ----
        #pragma unroll
        for (int im = 0; im < 2; ++im) {
            #pragma unroll
            for (int r = 0; r < 4; ++r) {
                const int mrow = wm2 * 32 + im * 16 + q * 4 + r;
                const float cc = sigf(acc[im][1][r]) * cst[im][r]
                               + sigf(acc[im][0][r]) * tanhfast(acc[im][2][r]);
                cst[im][r] = cc;
                const float hh = sigf(acc[im][3][r]) * tanhfast(cc);
                s_h[mrow * 136 + wg * 16 + l15] = (_Float16)hh;
            }
        }
        __syncthreads();
    }

    // ---- final rel-pos (t = SEQLEN-1) ----
    {
        const float sm = relpos16(s_h, s_whp, rp_r, rp_j, rp_p);
        if (rp_p == 0)
            out[(size_t)(SEQLEN - 1) * (BATCH * 2) + (size_t)(m0 + rp_r) * 2 + rp_j]
                = sm + s_bhp[rp_j];
    }
}

// ---------------------------------------------------------------------------
extern "C" void kernel_launch(void* const* d_in, const int* in_sizes, int n_in,
                              void* d_out, int out_size, void* d_ws, size_t ws_size,
                              hipStream_t stream)
{
    const float* last_pos_rel = (const float*)d_in[1];
    const float* enc          = (const float*)d_in[2];
    const float* zin          = (const float*)d_in[3];
    const float* W_ih         = (const float*)d_in[5];
    const float* W_hh         = (const float*)d_in[6];
    const float* b_ih         = (const float*)d_in[7];
    const float* b_hh         = (const float*)d_in[8];
    const float* W1           = (const float*)d_in[9];
    const float* b1           = (const float*)d_in[10];
    const float* W2           = (const float*)d_in[11];
    const float* b2           = (const float*)d_in[12];
    const float* W_sp         = (const float*)d_in[13];
    const float* b_sp         = (const float*)d_in[14];
    const float* W_hp         = (const float*)d_in[15];
    const float* b_hp         = (const float*)d_in[16];
    float* out = (float*)d_out;

    char* ws = (char*)d_ws;
    const bool big = (ws_size >= B_TOTAL);

    _Float16* wcat  = (_Float16*)(ws + (big ? B_WCAT_OFF  : S_WCAT_OFF));
    _Float16* w2h   = (_Float16*)(ws + (big ? B_W2H_OFF   : S_W2H_OFF));
    _Float16* whhf  = (_Float16*)(ws + (big ? B_WHHF_OFF  : S_WHHF_OFF));
    float*    wc    = (float*)(ws + (big ? B_WC_OFF    : S_WC_OFF));
    float*    bias2 = (float*)(ws + (big ? B_BIAS2_OFF : S_BIAS2_OFF));
    _Float16* t1    = (_Float16*)(ws + (big ? B_T1_OFF : S_T1_OFF));
    float*    gperm = (float*)(ws + (big ? B_GP_OFF : S_GP_OFF));
    _Float16* h0b   = (_Float16*)(ws + (big ? B_H0_OFF : S_H0_OFF));
    _Float16* zx16  = (_Float16*)(ws + B_ZX16_OFF);

    prep_kernel<<<dim3(1926), 256, 0, stream>>>(W_ih, W_hh, b_ih, b_hh, W1, W2, W_sp, b_sp,
                                                W_hp, big ? KP : ZX, wcat, w2h, whhf, wc, bias2);
    if (big) {
        zxcast_kernel<<<dim3(17408), 256, 0, stream>>>(enc, zin, zx16);
        gemm1_big_kernel<<<dim3(768), 512, 0, stream>>>(zx16, wcat, b1, bias2, t1, gperm);
    } else {
        gemm1_small_kernel<<<dim3(3072), 256, 0, stream>>>(enc, zin, wcat, b1, bias2, t1, gperm);
    }
    gemm2_kernel<<<dim3(512), 256, 0, stream>>>(t1, w2h, b2, h0b);
    recur_kernel<<<dim3(512), 1024, 0, stream>>>(gperm, h0b, whhf, wc, W_hp, b_hp,
                                                 last_pos_rel, out);
}

// Round 7
// 518.679 us; speedup vs baseline: 1.0253x; 1.0253x over previous
//
#include <hip/hip_runtime.h>

// ---------- problem constants ----------
#define BATCH   32768
#define SEQLEN  12
#define EMB     64
#define H       128
#define MLP     1024
#define Z       32
#define ZX      1056      // MLP + Z
#define KP      1088      // ZX padded to 17*64 (big path)
#define NG      512       // 4*H gates

typedef _Float16 f16x8 __attribute__((ext_vector_type(8)));
typedef float    f32x4 __attribute__((ext_vector_type(4)));

// ---------- workspace layouts ----------
// small path (ws < 217,651,200): round-3 layout, total 146,249,728
#define S_WCAT_OFF   0u
#define S_W2H_OFF    3244032u
#define S_WHHF_OFF   3506176u
#define S_WC_OFF     3637248u
#define S_BIAS2_OFF  3641344u
#define S_T1_OFF     3643392u
#define S_GP_OFF     70752256u
#define S_H0_OFF     137861120u
// big path: wcat stride 1088 + zx16 buffer, total 217,651,200
#define B_WCAT_OFF   0u           // 1536*1088*2 = 3,342,336
#define B_W2H_OFF    3342336u
#define B_WHHF_OFF   3604480u
#define B_WC_OFF     3735552u
#define B_BIAS2_OFF  3739648u
#define B_T1_OFF     3741696u
#define B_GP_OFF     70850560u
#define B_H0_OFF     137959424u
#define B_ZX16_OFF   146348032u
#define B_TOTAL      217651200ull

__device__ __forceinline__ float sigf(float x) {
    return __builtin_amdgcn_rcpf(1.0f + __expf(-x));
}
__device__ __forceinline__ float tanhfast(float x) {
    return 2.0f * __builtin_amdgcn_rcpf(1.0f + __expf(-2.0f * x)) - 1.0f;
}

// async global->LDS, 16B per lane. LDS dest = wave-uniform base + lane*16.
__device__ __forceinline__ void gload16(const void* g, void* l) {
    __builtin_amdgcn_global_load_lds(
        (const __attribute__((address_space(1))) unsigned int*)(unsigned long long)(uintptr_t)g,
        (__attribute__((address_space(3))) unsigned int*)(unsigned int)(uintptr_t)l,
        16, 0, 0);
}

// ---------------------------------------------------------------------------
// prep: pack weights fp16 (wcat stride = cs, zero-padded past 1056),
// fold biases, fold rel_pos feedback into W_hh.
// ---------------------------------------------------------------------------
__global__ __launch_bounds__(256) void prep_kernel(
    const float* __restrict__ W_ih, const float* __restrict__ W_hh_in,
    const float* __restrict__ b_ih, const float* __restrict__ b_hh,
    const float* __restrict__ W1,   const float* __restrict__ W2,
    const float* __restrict__ W_sp, const float* __restrict__ b_sp,
    const float* __restrict__ W_hp, int cs,
    _Float16* __restrict__ wcat, _Float16* __restrict__ w2h,
    _Float16* __restrict__ whhf, float* __restrict__ wc, float* __restrict__ bias2)
{
    const int bid = blockIdx.x;
    const int tid = threadIdx.x;
    if (bid < 1536) {
        const float* src = (bid < 1024) ? (W1 + (size_t)bid * ZX)
                                        : (W_ih + (size_t)(bid - 1024) * 1120);
        _Float16* dst = wcat + (size_t)bid * cs;
        for (int k = tid; k < cs; k += 256)
            dst[k] = (k < ZX) ? (_Float16)src[k] : (_Float16)0.f;
    } else if (bid < 1664) {
        const int n = bid - 1536;
        for (int k = tid; k < MLP; k += 256)
            w2h[n * MLP + k] = (_Float16)W2[n * MLP + k];
    } else if (bid < 1920) {
        const int n = (bid - 1664) * 2 + (tid >> 7);
        const int k = tid & 127;
        float wc0 = 0.f, wc1 = 0.f;
        for (int e = 0; e < EMB; ++e) {
            const float we = W_ih[(size_t)n * 1120 + ZX + e];
            wc0 += we * W_sp[e * 2];
            wc1 += we * W_sp[e * 2 + 1];
        }
        whhf[n * H + k] = (_Float16)(W_hh_in[n * H + k] + wc0 * W_hp[k] + wc1 * W_hp[H + k]);
    } else {
        const int t = (bid - 1920) * 256 + tid;
        if (t < 1024) {
            const int n = t >> 1, j = t & 1;
            float s = 0.f;
            for (int e = 0; e < EMB; ++e)
                s += W_ih[(size_t)n * 1120 + ZX + e] * W_sp[e * 2 + j];
            wc[t] = s;
        } else if (t < 1536) {
            const int n = t - 1024;
            float s = b_ih[n] + b_hh[n];
            for (int e = 0; e < EMB; ++e)
                s += W_ih[(size_t)n * 1120 + ZX + e] * b_sp[e];
            bias2[n] = s;
        }
    }
}

// ---------------------------------------------------------------------------
// zxcast (big path): zx16[32768][1088] = fp16([enc | z | zeros])
// 8 halfs per thread; grid = 4456448/256 = 17408 blocks.
// ---------------------------------------------------------------------------
__global__ __launch_bounds__(256) void zxcast_kernel(
    const float* __restrict__ enc, const float* __restrict__ zin,
    _Float16* __restrict__ zx16)
{
    const int gid = blockIdx.x * 256 + threadIdx.x;
    if (gid < 4194304) {                       // enc: 128 chunks/row
        const int row = gid >> 7, cw = gid & 127;
        const float4* s = (const float4*)(enc + (size_t)row * MLP + cw * 8);
        const float4 f0 = s[0], f1 = s[1];
        f16x8 v = {(_Float16)f0.x, (_Float16)f0.y, (_Float16)f0.z, (_Float16)f0.w,
                   (_Float16)f1.x, (_Float16)f1.y, (_Float16)f1.z, (_Float16)f1.w};
        *(f16x8*)(zx16 + (size_t)row * KP + cw * 8) = v;
    } else if (gid < 4325376) {                // z: 4 chunks/row
        const int g2 = gid - 4194304;
        const int row = g2 >> 2, cw = g2 & 3;
        const float4* s = (const float4*)(zin + (size_t)row * Z + cw * 8);
        const float4 f0 = s[0], f1 = s[1];
        f16x8 v = {(_Float16)f0.x, (_Float16)f0.y, (_Float16)f0.z, (_Float16)f0.w,
                   (_Float16)f1.x, (_Float16)f1.y, (_Float16)f1.z, (_Float16)f1.w};
        *(f16x8*)(zx16 + (size_t)row * KP + MLP + cw * 8) = v;
    } else {                                   // pad: 4 chunks/row of zeros
        const int g2 = gid - 4325376;
        const int row = g2 >> 2, cw = g2 & 3;
        f16x8 v = {};
        *(f16x8*)(zx16 + (size_t)row * KP + ZX + cw * 8) = v;
    }
}

// ---------------------------------------------------------------------------
// GEMM1 big path, round 5: 256x256 tile, BK=64, 512 thr (8 waves, 2M x 4N),
// 128 KB double-buffered LDS, 4-phase-per-K-tile schedule with counted
// vmcnt (T3+T4) + s_setprio around MFMA clusters (T5). Verified round 1.
// ---------------------------------------------------------------------------
__global__ __launch_bounds__(512, 2) void gemm1_big_kernel(
    const _Float16* __restrict__ zx16, const _Float16* __restrict__ wcat,
    const float* __restrict__ bias1, const float* __restrict__ bias2g,
    _Float16* __restrict__ t1, float* __restrict__ gperm)
{
    __shared__ _Float16 s_a[2][256 * 64];   // 64 KB
    __shared__ _Float16 s_b[2][256 * 64];   // 64 KB

    const int tid = threadIdx.x;
    const int b   = blockIdx.x;
    const int swz = (b & 7) * 96 + (b >> 3);
    const int mt  = swz / 6, nt = swz % 6;
    const int m0  = mt * 256, n0 = nt * 256;

    const int lane = tid & 63, wv = tid >> 6;
    const int wm   = wv >> 2,  wn = wv & 3;
    const int l15  = lane & 15, q = lane >> 4;

    const int rowS = tid >> 3;
    const int chS  = (tid & 7) ^ (rowS & 7);

    const _Float16* gA = zx16 + (size_t)(m0 + rowS) * KP + chS * 8;
    const _Float16* gB = wcat + (size_t)(n0 + rowS) * KP + chS * 8;
    const size_t rstep = (size_t)64 * KP;

    const int ph0  = q ^ (l15 & 7);           // k-slice 0
    const int ph1  = (4 + q) ^ (l15 & 7);     // k-slice 1
    const int aof0 = (wm * 128 + l15) * 64 + ph0 * 8;
    const int aof1 = (wm * 128 + l15) * 64 + ph1 * 8;
    const int bof0 = (wn * 64 + l15) * 64 + ph0 * 8;
    const int bof1 = (wn * 64 + l15) * 64 + ph1 * 8;

    f32x4 acc[8][4] = {};

    // prologue: stage K-tile 0 into buffer 0 (8 loads)
    {
        _Float16* dA = &s_a[0][0] + wv * 512;
        _Float16* dB = &s_b[0][0] + wv * 512;
        #pragma unroll
        for (int j = 0; j < 4; ++j) gload16(gA + j * rstep, dA + j * 4096);
        #pragma unroll
        for (int j = 0; j < 4; ++j) gload16(gB + j * rstep, dB + j * 4096);
    }

    #pragma unroll 2
    for (int kt = 0; kt < 16; ++kt) {
        const int cur = kt & 1;
        const _Float16* sA = &s_a[cur][0];
        const _Float16* sB = &s_b[cur][0];
        _Float16* dA = &s_a[cur ^ 1][0] + wv * 512;
        _Float16* dB = &s_b[cur ^ 1][0] + wv * 512;
        const _Float16* gA1 = gA + (kt + 1) * 64;
        const _Float16* gB1 = gB + (kt + 1) * 64;

        f16x8 af[4], bf[4];

        // ---- PH0: ks0/qm0; stage A-half0 of t+1; counted wait for tile t
        gload16(gA1,         dA);
        gload16(gA1 + rstep, dA + 4096);
        asm volatile("s_waitcnt vmcnt(2)\n\ts_barrier" ::: "memory");
        #pragma unroll
        for (int i = 0; i < 4; ++i) af[i] = *(const f16x8*)(sA + aof0 + i * 1024);
        #pragma unroll
        for (int i = 0; i < 4; ++i) bf[i] = *(const f16x8*)(sB + bof0 + i * 1024);
        __builtin_amdgcn_s_setprio(1);
        #pragma unroll
        for (int n_ = 0; n_ < 4; ++n_)
            #pragma unroll
            for (int m_ = 0; m_ < 4; ++m_)
                acc[m_][n_] = __builtin_amdgcn_mfma_f32_16x16x32_f16(af[m_], bf[n_], acc[m_][n_], 0, 0, 0);
        __builtin_amdgcn_s_setprio(0);
        asm volatile("s_barrier" ::: "memory");

        // ---- PH1: ks0/qm1; stage A-half1 of t+1 (bf ks0 reused in regs)
        gload16(gA1 + 2 * rstep, dA + 8192);
        gload16(gA1 + 3 * rstep, dA + 12288);
        #pragma unroll
        for (int i = 0; i < 4; ++i) af[i] = *(const f16x8*)(sA + aof0 + 4096 + i * 1024);
        asm volatile("s_barrier" ::: "memory");
        __builtin_amdgcn_s_setprio(1);
        #pragma unroll
        for (int n_ = 0; n_ < 4; ++n_)
            #pragma unroll
            for (int m_ = 0; m_ < 4; ++m_)
                acc[4 + m_][n_] = __builtin_amdgcn_mfma_f32_16x16x32_f16(af[m_], bf[n_], acc[4 + m_][n_], 0, 0, 0);
        __builtin_amdgcn_s_setprio(0);
        asm volatile("s_barrier" ::: "memory");

        // ---- PH2: ks1/qm0; stage B-half0 of t+1
        gload16(gB1,         dB);
        gload16(gB1 + rstep, dB + 4096);
        #pragma unroll
        for (int i = 0; i < 4; ++i) af[i] = *(const f16x8*)(sA + aof1 + i * 1024);
        #pragma unroll
        for (int i = 0; i < 4; ++i) bf[i] = *(const f16x8*)(sB + bof1 + i * 1024);
        asm volatile("s_barrier" ::: "memory");
        __builtin_amdgcn_s_setprio(1);
        #pragma unroll
        for (int n_ = 0; n_ < 4; ++n_)
            #pragma unroll
            for (int m_ = 0; m_ < 4; ++m_)
                acc[m_][n_] = __builtin_amdgcn_mfma_f32_16x16x32_f16(af[m_], bf[n_], acc[m_][n_], 0, 0, 0);
        __builtin_amdgcn_s_setprio(0);
        asm volatile("s_barrier" ::: "memory");

        // ---- PH3: ks1/qm1; stage B-half1 of t+1
        gload16(gB1 + 2 * rstep, dB + 8192);
        gload16(gB1 + 3 * rstep, dB + 12288);
        #pragma unroll
        for (int i = 0; i < 4; ++i) af[i] = *(const f16x8*)(sA + aof1 + 4096 + i * 1024);
        asm volatile("s_barrier" ::: "memory");
        __builtin_amdgcn_s_setprio(1);
        #pragma unroll
        for (int n_ = 0; n_ < 4; ++n_)
            #pragma unroll
            for (int m_ = 0; m_ < 4; ++m_)
                acc[4 + m_][n_] = __builtin_amdgcn_mfma_f32_16x16x32_f16(af[m_], bf[n_], acc[4 + m_][n_], 0, 0, 0);
        __builtin_amdgcn_s_setprio(0);
        asm volatile("s_barrier" ::: "memory");
    }

    // ---- tail: K-tile 16 (buffer 0), full drain allowed (no more stages)
    {
        const _Float16* sA = &s_a[0][0];
        const _Float16* sB = &s_b[0][0];
        asm volatile("s_waitcnt vmcnt(0)\n\ts_barrier" ::: "memory");
        f16x8 af[4], bf[4];
        #pragma unroll
        for (int i = 0; i < 4; ++i) af[i] = *(const f16x8*)(sA + aof0 + i * 1024);
        #pragma unroll
        for (int i = 0; i < 4; ++i) bf[i] = *(const f16x8*)(sB + bof0 + i * 1024);
        __builtin_amdgcn_s_setprio(1);
        #pragma unroll
        for (int n_ = 0; n_ < 4; ++n_)
            #pragma unroll
            for (int m_ = 0; m_ < 4; ++m_)
                acc[m_][n_] = __builtin_amdgcn_mfma_f32_16x16x32_f16(af[m_], bf[n_], acc[m_][n_], 0, 0, 0);
        #pragma unroll
        for (int i = 0; i < 4; ++i) af[i] = *(const f16x8*)(sA + aof0 + 4096 + i * 1024);
        #pragma unroll
        for (int n_ = 0; n_ < 4; ++n_)
            #pragma unroll
            for (int m_ = 0; m_ < 4; ++m_)
                acc[4 + m_][n_] = __builtin_amdgcn_mfma_f32_16x16x32_f16(af[m_], bf[n_], acc[4 + m_][n_], 0, 0, 0);
        #pragma unroll
        for (int i = 0; i < 4; ++i) af[i] = *(const f16x8*)(sA + aof1 + i * 1024);
        #pragma unroll
        for (int i = 0; i < 4; ++i) bf[i] = *(const f16x8*)(sB + bof1 + i * 1024);
        #pragma unroll
        for (int n_ = 0; n_ < 4; ++n_)
            #pragma unroll
            for (int m_ = 0; m_ < 4; ++m_)
                acc[m_][n_] = __builtin_amdgcn_mfma_f32_16x16x32_f16(af[m_], bf[n_], acc[m_][n_], 0, 0, 0);
        #pragma unroll
        for (int i = 0; i < 4; ++i) af[i] = *(const f16x8*)(sA + aof1 + 4096 + i * 1024);
        #pragma unroll
        for (int n_ = 0; n_ < 4; ++n_)
            #pragma unroll
            for (int m_ = 0; m_ < 4; ++m_)
                acc[4 + m_][n_] = __builtin_amdgcn_mfma_f32_16x16x32_f16(af[m_], bf[n_], acc[4 + m_][n_], 0, 0, 0);
        __builtin_amdgcn_s_setprio(0);
    }

    // ---- epilogue: nt<4 -> t1 (relu, fp16); nt>=4 -> gperm (fp32, permuted)
    if (nt < 4) {
        #pragma unroll
        for (int im = 0; im < 8; ++im)
            #pragma unroll
            for (int in_ = 0; in_ < 4; ++in_) {
                const int n = n0 + wn * 64 + in_ * 16 + l15;
                const float bb = bias1[n];
                const int mbase = m0 + wm * 128 + im * 16 + q * 4;
                #pragma unroll
                for (int r = 0; r < 4; ++r) {
                    float v = acc[im][in_][r] + bb;
                    v = v > 0.f ? v : 0.f;
                    t1[(size_t)(mbase + r) * MLP + n] = (_Float16)v;
                }
            }
    } else {
        #pragma unroll
        for (int im = 0; im < 8; ++im)
            #pragma unroll
            for (int in_ = 0; in_ < 4; ++in_) {
                const int n = (n0 - 1024) + wn * 64 + in_ * 16 + l15;
                const float bb = bias2g[n];
                const int m4 = (m0 + wm * 128 + im * 16 + q * 4) >> 2;
                float4 v;
                v.x = acc[im][in_][0] + bb;
                v.y = acc[im][in_][1] + bb;
                v.z = acc[im][in_][2] + bb;
                v.w = acc[im][in_][3] + bb;
                *(float4*)(gperm + ((size_t)m4 * NG + n) * 4) = v;
            }
    }
}

// ---------------------------------------------------------------------------
// GEMM1 small path: round-3 kernel verbatim (fp32 A, BK=32, stride 1056).
// ---------------------------------------------------------------------------
__global__ __launch_bounds__(256) void gemm1_small_kernel(
    const float* __restrict__ enc, const float* __restrict__ zin,
    const _Float16* __restrict__ wcat,
    const float* __restrict__ bias1, const float* __restrict__ bias2g,
    _Float16* __restrict__ t1, float* __restrict__ gperm)
{
    __shared__ float    s_a[128 * 32];
    __shared__ _Float16 s_b[128 * 32];

    const int tid = threadIdx.x;
    const int b = blockIdx.x;
    const int x = b & 7, s = b >> 3;
    const int mt = x * 32 + s / 12;
    const int bn = s % 12;
    const int m0 = mt * 128;

    const int lane = tid & 63, wv = tid >> 6;
    const int wm = wv >> 1, wn = wv & 1;
    const int l15 = lane & 15, q = lane >> 4;

    const int rowA = tid >> 3;
    const int chA  = (tid & 7) ^ ((tid >> 3) & 7);
    const int rowB = tid >> 2;
    const int chB  = (tid & 3) ^ ((tid >> 3) & 3);

    const int ca0 = (2 * q) ^ (l15 & 7);
    const int cb  = q ^ ((l15 >> 1) & 3);

    f32x4 acc[4][4] = {};

    for (int kt = 0; kt < 33; ++kt) {
        const float* abase;
        size_t astride;
        if (kt < 32) { abase = enc + (size_t)m0 * MLP + kt * 32; astride = MLP; }
        else         { abase = zin + (size_t)m0 * Z;             astride = Z;   }

        __syncthreads();
        #pragma unroll
        for (int i = 0; i < 4; ++i)
            gload16(abase + (size_t)(i * 32 + rowA) * astride + chA * 4,
                    s_a + i * 1024 + wv * 256);
        #pragma unroll
        for (int i = 0; i < 2; ++i)
            gload16(wcat + (size_t)(bn * 128 + i * 64 + rowB) * ZX + kt * 32 + chB * 8,
                    s_b + i * 2048 + wv * 512);
        __syncthreads();

        f16x8 af[4];
        #pragma unroll
        for (int im = 0; im < 4; ++im) {
            const float* ap = s_a + (wm * 64 + im * 16 + l15) * 32;
            const float4 f0 = *(const float4*)(ap + ca0 * 4);
            const float4 f1 = *(const float4*)(ap + (ca0 ^ 1) * 4);
            af[im] = f16x8{(_Float16)f0.x, (_Float16)f0.y, (_Float16)f0.z, (_Float16)f0.w,
                           (_Float16)f1.x, (_Float16)f1.y, (_Float16)f1.z, (_Float16)f1.w};
        }
        #pragma unroll
        for (int in_ = 0; in_ < 4; ++in_) {
            const f16x8 bf = *(const f16x8*)(s_b + (wn * 64 + in_ * 16 + l15) * 32 + cb * 8);
            #pragma unroll
            for (int im = 0; im < 4; ++im)
                acc[im][in_] = __builtin_amdgcn_mfma_f32_16x16x32_f16(af[im], bf, acc[im][in_], 0, 0, 0);
        }
    }

    if (bn < 8) {
        #pragma unroll
        for (int im = 0; im < 4; ++im)
            #pragma unroll
            for (int in_ = 0; in_ < 4; ++in_) {
                const int n = bn * 128 + wn * 64 + in_ * 16 + l15;
                const float bb = bias1[n];
                #pragma unroll
                for (int r = 0; r < 4; ++r) {
                    const int m = m0 + wm * 64 + im * 16 + q * 4 + r;
                    float v = acc[im][in_][r] + bb;
                    v = v > 0.f ? v : 0.f;
                    t1[(size_t)m * MLP + n] = (_Float16)v;
                }
            }
    } else {
        #pragma unroll
        for (int im = 0; im < 4; ++im)
            #pragma unroll
            for (int in_ = 0; in_ < 4; ++in_) {
                const int n = (bn - 8) * 128 + wn * 64 + in_ * 16 + l15;
                const float bb = bias2g[n];
                const int m4 = (m0 + wm * 64 + im * 16 + q * 4) >> 2;
                float4 v;
                v.x = acc[im][in_][0] + bb;
                v.y = acc[im][in_][1] + bb;
                v.z = acc[im][in_][2] + bb;
                v.w = acc[im][in_][3] + bb;
                *(float4*)(gperm + ((size_t)m4 * NG + n) * 4) = v;
            }
    }
}

// ---------------------------------------------------------------------------
// GEMM2 v2: h0[32768,128] = fp16(relu(t1 @ w2h.T + b2)). Tile 64x128,
// grid 512 -> 2 blocks/CU. Wave w: n-cols w*32 (2 frags), m 0..63 (4 frags).
// 4-chunk XOR-with-parity swizzle -> 2-way banks (free).
// ---------------------------------------------------------------------------
__global__ __launch_bounds__(256) void gemm2_kernel(
    const _Float16* __restrict__ t1, const _Float16* __restrict__ w2h,
    const float* __restrict__ b2, _Float16* __restrict__ h0buf)
{
    __shared__ _Float16 s_a[64 * 32];    // 4 KB
    __shared__ _Float16 s_b[128 * 32];   // 8 KB

    const int tid = threadIdx.x;
    const int m0  = blockIdx.x * 64;
    const int lane = tid & 63, wv = tid >> 6;
    const int l15 = lane & 15, q = lane >> 4;

    // staging: slot P -> row=P>>2, pch=P&3, logical c=(pch^row^(row>>2))&3
    const int rowS = tid >> 2;
    const int chS  = ((tid & 3) ^ (tid >> 2) ^ (tid >> 4)) & 3;
    // frag phys chunk: (q ^ l15 ^ (l15>>2)) & 3
    const int phF  = (q ^ l15 ^ (l15 >> 2)) & 3;

    f32x4 acc[4][2] = {};

    for (int kt = 0; kt < 32; ++kt) {
        __syncthreads();
        gload16(t1 + (size_t)(m0 + rowS) * MLP + kt * 32 + chS * 8,
                s_a + wv * 512);
        #pragma unroll
        for (int i = 0; i < 2; ++i) {
            const int row = i * 64 + rowS;
            const int c   = ((tid & 3) ^ row ^ (row >> 2)) & 3;
            gload16(w2h + (size_t)row * MLP + kt * 32 + c * 8,
                    s_b + i * 2048 + wv * 512);
        }
        __syncthreads();

        f16x8 af[4];
        #pragma unroll
        for (int im = 0; im < 4; ++im)
            af[im] = *(const f16x8*)(s_a + (im * 16 + l15) * 32 + phF * 8);
        #pragma unroll
        for (int in_ = 0; in_ < 2; ++in_) {
            const f16x8 bf = *(const f16x8*)(s_b + (wv * 32 + in_ * 16 + l15) * 32 + phF * 8);
            #pragma unroll
            for (int im = 0; im < 4; ++im)
                acc[im][in_] = __builtin_amdgcn_mfma_f32_16x16x32_f16(af[im], bf, acc[im][in_], 0, 0, 0);
        }
    }

    #pragma unroll
    for (int im = 0; im < 4; ++im)
        #pragma unroll
        for (int in_ = 0; in_ < 2; ++in_) {
            const int n = wv * 32 + in_ * 16 + l15;
            const float bb = b2[n];
            #pragma unroll
            for (int r = 0; r < 4; ++r) {
                const int m = m0 + im * 16 + q * 4 + r;
                float v = acc[im][in_][r] + bb;
                v = v > 0.f ? v : 0.f;
                h0buf[(size_t)m * H + n] = (_Float16)v;
            }
        }
}

// ---------------------------------------------------------------------------
// Recurrence, round 11: round-6 kernel (1024 thr = 16 waves = 4 waves/SIMD,
// verified correct, absmax 0.0039) with the VGPR allocator pinned to exactly
// 4 waves/EU via amdgpu_waves_per_eu(4,4). Round 6's launch_bounds(1024,4)
// set only a MINIMUM; the compiler squeezed to 64 VGPR chasing 8 waves/EU
// (impossible: LDS caps at 1 block/CU) and spilled ~120 MB/dispatch to
// scratch (WRITE_SIZE 3->121 MB). Pinning min=max=4 gives the full
// 128-VGPR budget for the ~110-VGPR live state -> no spills.
// ---------------------------------------------------------------------------
__device__ __forceinline__ float relpos16(const _Float16* s_h, const float* s_whp,
                                          int row, int j, int p) {
    const f16x8 a = *(const f16x8*)(s_h + row * 136 + p * 16);
    const f16x8 b = *(const f16x8*)(s_h + row * 136 + p * 16 + 8);
    const float* wp = s_whp + (j * 4 + (p >> 1)) * 36 + (p & 1) * 16;
    float s = 0.f;
    #pragma unroll
    for (int u = 0; u < 8; ++u)
        s += (float)a[u] * wp[u] + (float)b[u] * wp[8 + u];
    s += __shfl_down(s, 4, 64);
    s += __shfl_down(s, 2, 64);
    s += __shfl_down(s, 1, 64);
    return s;   // valid at p == 0
}

__global__ __launch_bounds__(1024)
__attribute__((amdgpu_waves_per_eu(4, 4)))
void recur_kernel(
    const float* __restrict__ gperm, const _Float16* __restrict__ h0buf,
    const _Float16* __restrict__ whhf, const float* __restrict__ wc,
    const float* __restrict__ whp, const float* __restrict__ bhp,
    const float* __restrict__ lpr, float* __restrict__ out)
{
    __shared__ _Float16 s_whh[512 * 136];
    __shared__ _Float16 s_h[64 * 136];
    __shared__ float    s_p[128];
    __shared__ float    s_wc[1024];
    __shared__ float    s_whp[8 * 36];   // [j*4+part][32 floats], +4 pad
    __shared__ float    s_bhp[2];

    const int tid = threadIdx.x;
    const int m0  = blockIdx.x * 64;
    const int lane = tid & 63;
    const int w16 = tid >> 6;           // 0..15
    const int wg  = w16 & 7;            // gate-column wave index
    const int wm2 = w16 >> 3;           // m-half
    const int l15 = lane & 15, q = lane >> 4;

    // ---- staging (mechanically re-mapped to 1024 threads) ----
    #pragma unroll
    for (int i = 0; i < 8; ++i) {
        const int cid = tid + i * 1024;
        const int row = cid >> 4, ch = cid & 15;
        *(uint4*)(s_whh + row * 136 + ch * 8) = *(const uint4*)(whhf + row * H + ch * 8);
    }
    if (tid < 256) *(float4*)(s_wc + tid * 4)  = *(const float4*)(wc + tid * 4);
    if (tid < 64) {
        const int jp = tid >> 3;            // 0..7 = j*4+part
        const int e8 = tid & 7;             // 4-float chunk 0..7
        const int j = jp >> 2, part = jp & 3;
        *(float4*)(s_whp + jp * 36 + e8 * 4) = *(const float4*)(whp + j * H + part * 32 + e8 * 4);
    }
    if (tid < 2)   s_bhp[tid] = bhp[tid];
    if (tid < 128) s_p[tid] = lpr[(size_t)m0 * 2 + tid];
    {
        const int row = tid >> 4, ch = tid & 15;
        *(uint4*)(s_h + row * 136 + ch * 8) = *(const uint4*)(h0buf + (size_t)(m0 + row) * H + ch * 8);
    }

    // gate-bias fragments from gperm
    f32x4 gb[2][4];
    #pragma unroll
    for (int im = 0; im < 2; ++im) {
        const int m4 = (m0 >> 2) + wm2 * 8 + im * 4 + q;
        #pragma unroll
        for (int g = 0; g < 4; ++g) {
            const float4 v = *(const float4*)(gperm + ((size_t)m4 * NG + g * H + wg * 16 + l15) * 4);
            gb[im][g] = f32x4{v.x, v.y, v.z, v.w};
        }
    }

    f32x4 cst[2] = {};

    __syncthreads();

    // ---- init: s_p -= h0 . whp (round-3 32-wide form, tid<512) ----
    if (tid < 512) {
        const int part = tid & 3;
        const int j    = (tid >> 2) & 1;
        const int row  = tid >> 3;
        const int jp   = j * 4 + part;
        float sum = 0.f;
        #pragma unroll
        for (int u = 0; u < 4; ++u) {
            const f16x8 hv = *(const f16x8*)(s_h + row * 136 + part * 32 + u * 8);
            const float4* wp = (const float4*)(s_whp + jp * 36 + u * 8);
            const float4 w0 = wp[0], w1 = wp[1];
            sum += (float)hv[0] * w0.x + (float)hv[1] * w0.y + (float)hv[2] * w0.z + (float)hv[3] * w0.w
                 + (float)hv[4] * w1.x + (float)hv[5] * w1.y + (float)hv[6] * w1.z + (float)hv[7] * w1.w;
        }
        sum += __shfl_down(sum, 2, 64);
        sum += __shfl_down(sum, 1, 64);
        if (part == 0) s_p[row * 2 + j] -= sum;
    }
    __syncthreads();

    float wc0[4], wc1[4], cg[4];
    #pragma unroll
    for (int g = 0; g < 4; ++g) {
        const int n = g * H + wg * 16 + l15;
        wc0[g] = s_wc[n * 2];
        wc1[g] = s_wc[n * 2 + 1];
        cg[g]  = wc0[g] * s_bhp[0] + wc1[g] * s_bhp[1];
    }
    #pragma unroll
    for (int im = 0; im < 2; ++im)
        #pragma unroll
        for (int r = 0; r < 4; ++r) {
            const int mrow = wm2 * 32 + im * 16 + q * 4 + r;
            const float pa = s_p[mrow * 2], pb = s_p[mrow * 2 + 1];
            #pragma unroll
            for (int g = 0; g < 4; ++g)
                gb[im][g][r] += pa * wc0[g] + pb * wc1[g];
        }

    const int rp_p = tid & 7, rp_j = (tid >> 3) & 1, rp_r = tid >> 4;  // rows 0..63

    for (int t = 0; t < SEQLEN; ++t) {
        // ---- phase A: MFMA gates(t) from s_h(t-1); rel-pos(t-1) hidden ----
        f32x4 acc[2][4];
        #pragma unroll
        for (int kt = 0; kt < 4; ++kt) {
            f16x8 af[2];
            #pragma unroll
            for (int im = 0; im < 2; ++im)
                af[im] = *(const f16x8*)(s_h + (wm2 * 32 + im * 16 + l15) * 136 + kt * 32 + q * 8);
            #pragma unroll
            for (int g = 0; g < 4; ++g) {
                const f16x8 bf = *(const f16x8*)(s_whh + (g * H + wg * 16 + l15) * 136 + kt * 32 + q * 8);
                #pragma unroll
                for (int im = 0; im < 2; ++im)
                    acc[im][g] = __builtin_amdgcn_mfma_f32_16x16x32_f16(
                        af[im], bf, (kt == 0) ? gb[im][g] : acc[im][g], 0, 0, 0);
            }
        }
        if (t > 0) {
            const float sm = relpos16(s_h, s_whp, rp_r, rp_j, rp_p);
            if (rp_p == 0)
                out[(size_t)(t - 1) * (BATCH * 2) + (size_t)(m0 + rp_r) * 2 + rp_j]
                    = sm + s_bhp[rp_j];
        } else {
            #pragma unroll
            for (int im = 0; im < 2; ++im)
                #pragma unroll
                for (int r = 0; r < 4; ++r) {
                    const int mrow = wm2 * 32 + im * 16 + q * 4 + r;
                    const float pa = s_p[mrow * 2], pb = s_p[mrow * 2 + 1];
                    #pragma unroll
                    for (int g = 0; g < 4; ++g)
                        gb[im][g][r] += cg[g] - (pa * wc0[g] + pb * wc1[g]);
                }
        }
        __syncthreads();

        // ---- phase B: LSTM cell update, write s_h(t) ----
        #pragma unroll
        for (int im = 0; im < 2; ++im) {
            #pragma unroll
            for (int r = 0; r < 4; ++r) {
                const int mrow = wm2 * 32 + im * 16 + q * 4 + r;
                const float cc = sigf(acc[im][1][r]) * cst[im][r]
                               + sigf(acc[im][0][r]) * tanhfast(acc[im][2][r]);
                cst[im][r] = cc;
                const float hh = sigf(acc[im][3][r]) * tanhfast(cc);
                s_h[mrow * 136 + wg * 16 + l15] = (_Float16)hh;
            }
        }
        __syncthreads();
    }

    // ---- final rel-pos (t = SEQLEN-1) ----
    {
        const float sm = relpos16(s_h, s_whp, rp_r, rp_j, rp_p);
        if (rp_p == 0)
            out[(size_t)(SEQLEN - 1) * (BATCH * 2) + (size_t)(m0 + rp_r) * 2 + rp_j]
                = sm + s_bhp[rp_j];
    }
}

// ---------------------------------------------------------------------------
extern "C" void kernel_launch(void* const* d_in, const int* in_sizes, int n_in,
                              void* d_out, int out_size, void* d_ws, size_t ws_size,
                              hipStream_t stream)
{
    const float* last_pos_rel = (const float*)d_in[1];
    const float* enc          = (const float*)d_in[2];
    const float* zin          = (const float*)d_in[3];
    const float* W_ih         = (const float*)d_in[5];
    const float* W_hh         = (const float*)d_in[6];
    const float* b_ih         = (const float*)d_in[7];
    const float* b_hh         = (const float*)d_in[8];
    const float* W1           = (const float*)d_in[9];
    const float* b1           = (const float*)d_in[10];
    const float* W2           = (const float*)d_in[11];
    const float* b2           = (const float*)d_in[12];
    const float* W_sp         = (const float*)d_in[13];
    const float* b_sp         = (const float*)d_in[14];
    const float* W_hp         = (const float*)d_in[15];
    const float* b_hp         = (const float*)d_in[16];
    float* out = (float*)d_out;

    char* ws = (char*)d_ws;
    const bool big = (ws_size >= B_TOTAL);

    _Float16* wcat  = (_Float16*)(ws + (big ? B_WCAT_OFF  : S_WCAT_OFF));
    _Float16* w2h   = (_Float16*)(ws + (big ? B_W2H_OFF   : S_W2H_OFF));
    _Float16* whhf  = (_Float16*)(ws + (big ? B_WHHF_OFF  : S_WHHF_OFF));
    float*    wc    = (float*)(ws + (big ? B_WC_OFF    : S_WC_OFF));
    float*    bias2 = (float*)(ws + (big ? B_BIAS2_OFF : S_BIAS2_OFF));
    _Float16* t1    = (_Float16*)(ws + (big ? B_T1_OFF : S_T1_OFF));
    float*    gperm = (float*)(ws + (big ? B_GP_OFF : S_GP_OFF));
    _Float16* h0b   = (_Float16*)(ws + (big ? B_H0_OFF : S_H0_OFF));
    _Float16* zx16  = (_Float16*)(ws + B_ZX16_OFF);

    prep_kernel<<<dim3(1926), 256, 0, stream>>>(W_ih, W_hh, b_ih, b_hh, W1, W2, W_sp, b_sp,
                                                W_hp, big ? KP : ZX, wcat, w2h, whhf, wc, bias2);
    if (big) {
        zxcast_kernel<<<dim3(17408), 256, 0, stream>>>(enc, zin, zx16);
        gemm1_big_kernel<<<dim3(768), 512, 0, stream>>>(zx16, wcat, b1, bias2, t1, gperm);
    } else {
        gemm1_small_kernel<<<dim3(3072), 256, 0, stream>>>(enc, zin, wcat, b1, bias2, t1, gperm);
    }
    gemm2_kernel<<<dim3(512), 256, 0, stream>>>(t1, w2h, b2, h0b);
    recur_kernel<<<dim3(512), 1024, 0, stream>>>(gperm, h0b, whhf, wc, W_hp, b_hp,
                                                 last_pos_rel, out);
}

// Round 8
// 514.461 us; speedup vs baseline: 1.0337x; 1.0082x over previous
//
#include <hip/hip_runtime.h>

// ---------- problem constants ----------
#define BATCH   32768
#define SEQLEN  12
#define EMB     64
#define H       128
#define MLP     1024
#define Z       32
#define ZX      1056      // MLP + Z
#define KP      1088      // ZX padded to 17*64 (big path)
#define NG      512       // 4*H gates

typedef _Float16 f16x8 __attribute__((ext_vector_type(8)));
typedef float    f32x4 __attribute__((ext_vector_type(4)));

// ---------- workspace layouts ----------
// small path (ws < 217,651,200): round-3 layout, total 146,249,728
#define S_WCAT_OFF   0u
#define S_W2H_OFF    3244032u
#define S_WHHF_OFF   3506176u
#define S_WC_OFF     3637248u
#define S_BIAS2_OFF  3641344u
#define S_T1_OFF     3643392u
#define S_GP_OFF     70752256u
#define S_H0_OFF     137861120u
// big path: wcat stride 1088 + zx16 buffer, total 217,651,200
#define B_WCAT_OFF   0u           // 1536*1088*2 = 3,342,336
#define B_W2H_OFF    3342336u
#define B_WHHF_OFF   3604480u
#define B_WC_OFF     3735552u
#define B_BIAS2_OFF  3739648u
#define B_T1_OFF     3741696u
#define B_GP_OFF     70850560u
#define B_H0_OFF     137959424u
#define B_ZX16_OFF   146348032u
#define B_TOTAL      217651200ull

__device__ __forceinline__ float sigf(float x) {
    return __builtin_amdgcn_rcpf(1.0f + __expf(-x));
}
__device__ __forceinline__ float tanhfast(float x) {
    return 2.0f * __builtin_amdgcn_rcpf(1.0f + __expf(-2.0f * x)) - 1.0f;
}

// async global->LDS, 16B per lane. LDS dest = wave-uniform base + lane*16.
__device__ __forceinline__ void gload16(const void* g, void* l) {
    __builtin_amdgcn_global_load_lds(
        (const __attribute__((address_space(1))) unsigned int*)(unsigned long long)(uintptr_t)g,
        (__attribute__((address_space(3))) unsigned int*)(unsigned int)(uintptr_t)l,
        16, 0, 0);
}

// ---------------------------------------------------------------------------
// prep: pack weights fp16 (wcat stride = cs, zero-padded past 1056),
// fold biases, fold rel_pos feedback into W_hh.
// ---------------------------------------------------------------------------
__global__ __launch_bounds__(256) void prep_kernel(
    const float* __restrict__ W_ih, const float* __restrict__ W_hh_in,
    const float* __restrict__ b_ih, const float* __restrict__ b_hh,
    const float* __restrict__ W1,   const float* __restrict__ W2,
    const float* __restrict__ W_sp, const float* __restrict__ b_sp,
    const float* __restrict__ W_hp, int cs,
    _Float16* __restrict__ wcat, _Float16* __restrict__ w2h,
    _Float16* __restrict__ whhf, float* __restrict__ wc, float* __restrict__ bias2)
{
    const int bid = blockIdx.x;
    const int tid = threadIdx.x;
    if (bid < 1536) {
        const float* src = (bid < 1024) ? (W1 + (size_t)bid * ZX)
                                        : (W_ih + (size_t)(bid - 1024) * 1120);
        _Float16* dst = wcat + (size_t)bid * cs;
        for (int k = tid; k < cs; k += 256)
            dst[k] = (k < ZX) ? (_Float16)src[k] : (_Float16)0.f;
    } else if (bid < 1664) {
        const int n = bid - 1536;
        for (int k = tid; k < MLP; k += 256)
            w2h[n * MLP + k] = (_Float16)W2[n * MLP + k];
    } else if (bid < 1920) {
        const int n = (bid - 1664) * 2 + (tid >> 7);
        const int k = tid & 127;
        float wc0 = 0.f, wc1 = 0.f;
        for (int e = 0; e < EMB; ++e) {
            const float we = W_ih[(size_t)n * 1120 + ZX + e];
            wc0 += we * W_sp[e * 2];
            wc1 += we * W_sp[e * 2 + 1];
        }
        whhf[n * H + k] = (_Float16)(W_hh_in[n * H + k] + wc0 * W_hp[k] + wc1 * W_hp[H + k]);
    } else {
        const int t = (bid - 1920) * 256 + tid;
        if (t < 1024) {
            const int n = t >> 1, j = t & 1;
            float s = 0.f;
            for (int e = 0; e < EMB; ++e)
                s += W_ih[(size_t)n * 1120 + ZX + e] * W_sp[e * 2 + j];
            wc[t] = s;
        } else if (t < 1536) {
            const int n = t - 1024;
            float s = b_ih[n] + b_hh[n];
            for (int e = 0; e < EMB; ++e)
                s += W_ih[(size_t)n * 1120 + ZX + e] * b_sp[e];
            bias2[n] = s;
        }
    }
}

// ---------------------------------------------------------------------------
// zxcast (big path): zx16[32768][1088] = fp16([enc | z | zeros])
// 8 halfs per thread; grid = 4456448/256 = 17408 blocks.
// ---------------------------------------------------------------------------
__global__ __launch_bounds__(256) void zxcast_kernel(
    const float* __restrict__ enc, const float* __restrict__ zin,
    _Float16* __restrict__ zx16)
{
    const int gid = blockIdx.x * 256 + threadIdx.x;
    if (gid < 4194304) {                       // enc: 128 chunks/row
        const int row = gid >> 7, cw = gid & 127;
        const float4* s = (const float4*)(enc + (size_t)row * MLP + cw * 8);
        const float4 f0 = s[0], f1 = s[1];
        f16x8 v = {(_Float16)f0.x, (_Float16)f0.y, (_Float16)f0.z, (_Float16)f0.w,
                   (_Float16)f1.x, (_Float16)f1.y, (_Float16)f1.z, (_Float16)f1.w};
        *(f16x8*)(zx16 + (size_t)row * KP + cw * 8) = v;
    } else if (gid < 4325376) {                // z: 4 chunks/row
        const int g2 = gid - 4194304;
        const int row = g2 >> 2, cw = g2 & 3;
        const float4* s = (const float4*)(zin + (size_t)row * Z + cw * 8);
        const float4 f0 = s[0], f1 = s[1];
        f16x8 v = {(_Float16)f0.x, (_Float16)f0.y, (_Float16)f0.z, (_Float16)f0.w,
                   (_Float16)f1.x, (_Float16)f1.y, (_Float16)f1.z, (_Float16)f1.w};
        *(f16x8*)(zx16 + (size_t)row * KP + MLP + cw * 8) = v;
    } else {                                   // pad: 4 chunks/row of zeros
        const int g2 = gid - 4325376;
        const int row = g2 >> 2, cw = g2 & 3;
        f16x8 v = {};
        *(f16x8*)(zx16 + (size_t)row * KP + ZX + cw * 8) = v;
    }
}

// ---------------------------------------------------------------------------
// GEMM1 big path, round 5: 256x256 tile, BK=64, 512 thr (8 waves, 2M x 4N),
// 128 KB double-buffered LDS, 4-phase-per-K-tile schedule with counted
// vmcnt (T3+T4) + s_setprio around MFMA clusters (T5). Verified round 1.
// ---------------------------------------------------------------------------
__global__ __launch_bounds__(512, 2) void gemm1_big_kernel(
    const _Float16* __restrict__ zx16, const _Float16* __restrict__ wcat,
    const float* __restrict__ bias1, const float* __restrict__ bias2g,
    _Float16* __restrict__ t1, float* __restrict__ gperm)
{
    __shared__ _Float16 s_a[2][256 * 64];   // 64 KB
    __shared__ _Float16 s_b[2][256 * 64];   // 64 KB

    const int tid = threadIdx.x;
    const int b   = blockIdx.x;
    const int swz = (b & 7) * 96 + (b >> 3);
    const int mt  = swz / 6, nt = swz % 6;
    const int m0  = mt * 256, n0 = nt * 256;

    const int lane = tid & 63, wv = tid >> 6;
    const int wm   = wv >> 2,  wn = wv & 3;
    const int l15  = lane & 15, q = lane >> 4;

    const int rowS = tid >> 3;
    const int chS  = (tid & 7) ^ (rowS & 7);

    const _Float16* gA = zx16 + (size_t)(m0 + rowS) * KP + chS * 8;
    const _Float16* gB = wcat + (size_t)(n0 + rowS) * KP + chS * 8;
    const size_t rstep = (size_t)64 * KP;

    const int ph0  = q ^ (l15 & 7);           // k-slice 0
    const int ph1  = (4 + q) ^ (l15 & 7);     // k-slice 1
    const int aof0 = (wm * 128 + l15) * 64 + ph0 * 8;
    const int aof1 = (wm * 128 + l15) * 64 + ph1 * 8;
    const int bof0 = (wn * 64 + l15) * 64 + ph0 * 8;
    const int bof1 = (wn * 64 + l15) * 64 + ph1 * 8;

    f32x4 acc[8][4] = {};

    // prologue: stage K-tile 0 into buffer 0 (8 loads)
    {
        _Float16* dA = &s_a[0][0] + wv * 512;
        _Float16* dB = &s_b[0][0] + wv * 512;
        #pragma unroll
        for (int j = 0; j < 4; ++j) gload16(gA + j * rstep, dA + j * 4096);
        #pragma unroll
        for (int j = 0; j < 4; ++j) gload16(gB + j * rstep, dB + j * 4096);
    }

    #pragma unroll 2
    for (int kt = 0; kt < 16; ++kt) {
        const int cur = kt & 1;
        const _Float16* sA = &s_a[cur][0];
        const _Float16* sB = &s_b[cur][0];
        _Float16* dA = &s_a[cur ^ 1][0] + wv * 512;
        _Float16* dB = &s_b[cur ^ 1][0] + wv * 512;
        const _Float16* gA1 = gA + (kt + 1) * 64;
        const _Float16* gB1 = gB + (kt + 1) * 64;

        f16x8 af[4], bf[4];

        // ---- PH0: ks0/qm0; stage A-half0 of t+1; counted wait for tile t
        gload16(gA1,         dA);
        gload16(gA1 + rstep, dA + 4096);
        asm volatile("s_waitcnt vmcnt(2)\n\ts_barrier" ::: "memory");
        #pragma unroll
        for (int i = 0; i < 4; ++i) af[i] = *(const f16x8*)(sA + aof0 + i * 1024);
        #pragma unroll
        for (int i = 0; i < 4; ++i) bf[i] = *(const f16x8*)(sB + bof0 + i * 1024);
        __builtin_amdgcn_s_setprio(1);
        #pragma unroll
        for (int n_ = 0; n_ < 4; ++n_)
            #pragma unroll
            for (int m_ = 0; m_ < 4; ++m_)
                acc[m_][n_] = __builtin_amdgcn_mfma_f32_16x16x32_f16(af[m_], bf[n_], acc[m_][n_], 0, 0, 0);
        __builtin_amdgcn_s_setprio(0);
        asm volatile("s_barrier" ::: "memory");

        // ---- PH1: ks0/qm1; stage A-half1 of t+1 (bf ks0 reused in regs)
        gload16(gA1 + 2 * rstep, dA + 8192);
        gload16(gA1 + 3 * rstep, dA + 12288);
        #pragma unroll
        for (int i = 0; i < 4; ++i) af[i] = *(const f16x8*)(sA + aof0 + 4096 + i * 1024);
        asm volatile("s_barrier" ::: "memory");
        __builtin_amdgcn_s_setprio(1);
        #pragma unroll
        for (int n_ = 0; n_ < 4; ++n_)
            #pragma unroll
            for (int m_ = 0; m_ < 4; ++m_)
                acc[4 + m_][n_] = __builtin_amdgcn_mfma_f32_16x16x32_f16(af[m_], bf[n_], acc[4 + m_][n_], 0, 0, 0);
        __builtin_amdgcn_s_setprio(0);
        asm volatile("s_barrier" ::: "memory");

        // ---- PH2: ks1/qm0; stage B-half0 of t+1
        gload16(gB1,         dB);
        gload16(gB1 + rstep, dB + 4096);
        #pragma unroll
        for (int i = 0; i < 4; ++i) af[i] = *(const f16x8*)(sA + aof1 + i * 1024);
        #pragma unroll
        for (int i = 0; i < 4; ++i) bf[i] = *(const f16x8*)(sB + bof1 + i * 1024);
        asm volatile("s_barrier" ::: "memory");
        __builtin_amdgcn_s_setprio(1);
        #pragma unroll
        for (int n_ = 0; n_ < 4; ++n_)
            #pragma unroll
            for (int m_ = 0; m_ < 4; ++m_)
                acc[m_][n_] = __builtin_amdgcn_mfma_f32_16x16x32_f16(af[m_], bf[n_], acc[m_][n_], 0, 0, 0);
        __builtin_amdgcn_s_setprio(0);
        asm volatile("s_barrier" ::: "memory");

        // ---- PH3: ks1/qm1; stage B-half1 of t+1
        gload16(gB1 + 2 * rstep, dB + 8192);
        gload16(gB1 + 3 * rstep, dB + 12288);
        #pragma unroll
        for (int i = 0; i < 4; ++i) af[i] = *(const f16x8*)(sA + aof1 + 4096 + i * 1024);
        asm volatile("s_barrier" ::: "memory");
        __builtin_amdgcn_s_setprio(1);
        #pragma unroll
        for (int n_ = 0; n_ < 4; ++n_)
            #pragma unroll
            for (int m_ = 0; m_ < 4; ++m_)
                acc[4 + m_][n_] = __builtin_amdgcn_mfma_f32_16x16x32_f16(af[m_], bf[n_], acc[4 + m_][n_], 0, 0, 0);
        __builtin_amdgcn_s_setprio(0);
        asm volatile("s_barrier" ::: "memory");
    }

    // ---- tail: K-tile 16 (buffer 0), full drain allowed (no more stages)
    {
        const _Float16* sA = &s_a[0][0];
        const _Float16* sB = &s_b[0][0];
        asm volatile("s_waitcnt vmcnt(0)\n\ts_barrier" ::: "memory");
        f16x8 af[4], bf[4];
        #pragma unroll
        for (int i = 0; i < 4; ++i) af[i] = *(const f16x8*)(sA + aof0 + i * 1024);
        #pragma unroll
        for (int i = 0; i < 4; ++i) bf[i] = *(const f16x8*)(sB + bof0 + i * 1024);
        __builtin_amdgcn_s_setprio(1);
        #pragma unroll
        for (int n_ = 0; n_ < 4; ++n_)
            #pragma unroll
            for (int m_ = 0; m_ < 4; ++m_)
                acc[m_][n_] = __builtin_amdgcn_mfma_f32_16x16x32_f16(af[m_], bf[n_], acc[m_][n_], 0, 0, 0);
        #pragma unroll
        for (int i = 0; i < 4; ++i) af[i] = *(const f16x8*)(sA + aof0 + 4096 + i * 1024);
        #pragma unroll
        for (int n_ = 0; n_ < 4; ++n_)
            #pragma unroll
            for (int m_ = 0; m_ < 4; ++m_)
                acc[4 + m_][n_] = __builtin_amdgcn_mfma_f32_16x16x32_f16(af[m_], bf[n_], acc[4 + m_][n_], 0, 0, 0);
        #pragma unroll
        for (int i = 0; i < 4; ++i) af[i] = *(const f16x8*)(sA + aof1 + i * 1024);
        #pragma unroll
        for (int i = 0; i < 4; ++i) bf[i] = *(const f16x8*)(sB + bof1 + i * 1024);
        #pragma unroll
        for (int n_ = 0; n_ < 4; ++n_)
            #pragma unroll
            for (int m_ = 0; m_ < 4; ++m_)
                acc[m_][n_] = __builtin_amdgcn_mfma_f32_16x16x32_f16(af[m_], bf[n_], acc[m_][n_], 0, 0, 0);
        #pragma unroll
        for (int i = 0; i < 4; ++i) af[i] = *(const f16x8*)(sA + aof1 + 4096 + i * 1024);
        #pragma unroll
        for (int n_ = 0; n_ < 4; ++n_)
            #pragma unroll
            for (int m_ = 0; m_ < 4; ++m_)
                acc[4 + m_][n_] = __builtin_amdgcn_mfma_f32_16x16x32_f16(af[m_], bf[n_], acc[4 + m_][n_], 0, 0, 0);
        __builtin_amdgcn_s_setprio(0);
    }

    // ---- epilogue: nt<4 -> t1 (relu, fp16); nt>=4 -> gperm (fp32, permuted)
    if (nt < 4) {
        #pragma unroll
        for (int im = 0; im < 8; ++im)
            #pragma unroll
            for (int in_ = 0; in_ < 4; ++in_) {
                const int n = n0 + wn * 64 + in_ * 16 + l15;
                const float bb = bias1[n];
                const int mbase = m0 + wm * 128 + im * 16 + q * 4;
                #pragma unroll
                for (int r = 0; r < 4; ++r) {
                    float v = acc[im][in_][r] + bb;
                    v = v > 0.f ? v : 0.f;
                    t1[(size_t)(mbase + r) * MLP + n] = (_Float16)v;
                }
            }
    } else {
        #pragma unroll
        for (int im = 0; im < 8; ++im)
            #pragma unroll
            for (int in_ = 0; in_ < 4; ++in_) {
                const int n = (n0 - 1024) + wn * 64 + in_ * 16 + l15;
                const float bb = bias2g[n];
                const int m4 = (m0 + wm * 128 + im * 16 + q * 4) >> 2;
                float4 v;
                v.x = acc[im][in_][0] + bb;
                v.y = acc[im][in_][1] + bb;
                v.z = acc[im][in_][2] + bb;
                v.w = acc[im][in_][3] + bb;
                *(float4*)(gperm + ((size_t)m4 * NG + n) * 4) = v;
            }
    }
}

// ---------------------------------------------------------------------------
// GEMM1 small path: round-3 kernel verbatim (fp32 A, BK=32, stride 1056).
// ---------------------------------------------------------------------------
__global__ __launch_bounds__(256) void gemm1_small_kernel(
    const float* __restrict__ enc, const float* __restrict__ zin,
    const _Float16* __restrict__ wcat,
    const float* __restrict__ bias1, const float* __restrict__ bias2g,
    _Float16* __restrict__ t1, float* __restrict__ gperm)
{
    __shared__ float    s_a[128 * 32];
    __shared__ _Float16 s_b[128 * 32];

    const int tid = threadIdx.x;
    const int b = blockIdx.x;
    const int x = b & 7, s = b >> 3;
    const int mt = x * 32 + s / 12;
    const int bn = s % 12;
    const int m0 = mt * 128;

    const int lane = tid & 63, wv = tid >> 6;
    const int wm = wv >> 1, wn = wv & 1;
    const int l15 = lane & 15, q = lane >> 4;

    const int rowA = tid >> 3;
    const int chA  = (tid & 7) ^ ((tid >> 3) & 7);
    const int rowB = tid >> 2;
    const int chB  = (tid & 3) ^ ((tid >> 3) & 3);

    const int ca0 = (2 * q) ^ (l15 & 7);
    const int cb  = q ^ ((l15 >> 1) & 3);

    f32x4 acc[4][4] = {};

    for (int kt = 0; kt < 33; ++kt) {
        const float* abase;
        size_t astride;
        if (kt < 32) { abase = enc + (size_t)m0 * MLP + kt * 32; astride = MLP; }
        else         { abase = zin + (size_t)m0 * Z;             astride = Z;   }

        __syncthreads();
        #pragma unroll
        for (int i = 0; i < 4; ++i)
            gload16(abase + (size_t)(i * 32 + rowA) * astride + chA * 4,
                    s_a + i * 1024 + wv * 256);
        #pragma unroll
        for (int i = 0; i < 2; ++i)
            gload16(wcat + (size_t)(bn * 128 + i * 64 + rowB) * ZX + kt * 32 + chB * 8,
                    s_b + i * 2048 + wv * 512);
        __syncthreads();

        f16x8 af[4];
        #pragma unroll
        for (int im = 0; im < 4; ++im) {
            const float* ap = s_a + (wm * 64 + im * 16 + l15) * 32;
            const float4 f0 = *(const float4*)(ap + ca0 * 4);
            const float4 f1 = *(const float4*)(ap + (ca0 ^ 1) * 4);
            af[im] = f16x8{(_Float16)f0.x, (_Float16)f0.y, (_Float16)f0.z, (_Float16)f0.w,
                           (_Float16)f1.x, (_Float16)f1.y, (_Float16)f1.z, (_Float16)f1.w};
        }
        #pragma unroll
        for (int in_ = 0; in_ < 4; ++in_) {
            const f16x8 bf = *(const f16x8*)(s_b + (wn * 64 + in_ * 16 + l15) * 32 + cb * 8);
            #pragma unroll
            for (int im = 0; im < 4; ++im)
                acc[im][in_] = __builtin_amdgcn_mfma_f32_16x16x32_f16(af[im], bf, acc[im][in_], 0, 0, 0);
        }
    }

    if (bn < 8) {
        #pragma unroll
        for (int im = 0; im < 4; ++im)
            #pragma unroll
            for (int in_ = 0; in_ < 4; ++in_) {
                const int n = bn * 128 + wn * 64 + in_ * 16 + l15;
                const float bb = bias1[n];
                #pragma unroll
                for (int r = 0; r < 4; ++r) {
                    const int m = m0 + wm * 64 + im * 16 + q * 4 + r;
                    float v = acc[im][in_][r] + bb;
                    v = v > 0.f ? v : 0.f;
                    t1[(size_t)m * MLP + n] = (_Float16)v;
                }
            }
    } else {
        #pragma unroll
        for (int im = 0; im < 4; ++im)
            #pragma unroll
            for (int in_ = 0; in_ < 4; ++in_) {
                const int n = (bn - 8) * 128 + wn * 64 + in_ * 16 + l15;
                const float bb = bias2g[n];
                const int m4 = (m0 + wm * 64 + im * 16 + q * 4) >> 2;
                float4 v;
                v.x = acc[im][in_][0] + bb;
                v.y = acc[im][in_][1] + bb;
                v.z = acc[im][in_][2] + bb;
                v.w = acc[im][in_][3] + bb;
                *(float4*)(gperm + ((size_t)m4 * NG + n) * 4) = v;
            }
    }
}

// ---------------------------------------------------------------------------
// GEMM2 v2: h0[32768,128] = fp16(relu(t1 @ w2h.T + b2)). Tile 64x128,
// grid 512 -> 2 blocks/CU. Wave w: n-cols w*32 (2 frags), m 0..63 (4 frags).
// 4-chunk XOR-with-parity swizzle -> 2-way banks (free).
// ---------------------------------------------------------------------------
__global__ __launch_bounds__(256) void gemm2_kernel(
    const _Float16* __restrict__ t1, const _Float16* __restrict__ w2h,
    const float* __restrict__ b2, _Float16* __restrict__ h0buf)
{
    __shared__ _Float16 s_a[64 * 32];    // 4 KB
    __shared__ _Float16 s_b[128 * 32];   // 8 KB

    const int tid = threadIdx.x;
    const int m0  = blockIdx.x * 64;
    const int lane = tid & 63, wv = tid >> 6;
    const int l15 = lane & 15, q = lane >> 4;

    // staging: slot P -> row=P>>2, pch=P&3, logical c=(pch^row^(row>>2))&3
    const int rowS = tid >> 2;
    const int chS  = ((tid & 3) ^ (tid >> 2) ^ (tid >> 4)) & 3;
    // frag phys chunk: (q ^ l15 ^ (l15>>2)) & 3
    const int phF  = (q ^ l15 ^ (l15 >> 2)) & 3;

    f32x4 acc[4][2] = {};

    for (int kt = 0; kt < 32; ++kt) {
        __syncthreads();
        gload16(t1 + (size_t)(m0 + rowS) * MLP + kt * 32 + chS * 8,
                s_a + wv * 512);
        #pragma unroll
        for (int i = 0; i < 2; ++i) {
            const int row = i * 64 + rowS;
            const int c   = ((tid & 3) ^ row ^ (row >> 2)) & 3;
            gload16(w2h + (size_t)row * MLP + kt * 32 + c * 8,
                    s_b + i * 2048 + wv * 512);
        }
        __syncthreads();

        f16x8 af[4];
        #pragma unroll
        for (int im = 0; im < 4; ++im)
            af[im] = *(const f16x8*)(s_a + (im * 16 + l15) * 32 + phF * 8);
        #pragma unroll
        for (int in_ = 0; in_ < 2; ++in_) {
            const f16x8 bf = *(const f16x8*)(s_b + (wv * 32 + in_ * 16 + l15) * 32 + phF * 8);
            #pragma unroll
            for (int im = 0; im < 4; ++im)
                acc[im][in_] = __builtin_amdgcn_mfma_f32_16x16x32_f16(af[im], bf, acc[im][in_], 0, 0, 0);
        }
    }

    #pragma unroll
    for (int im = 0; im < 4; ++im)
        #pragma unroll
        for (int in_ = 0; in_ < 2; ++in_) {
            const int n = wv * 32 + in_ * 16 + l15;
            const float bb = b2[n];
            #pragma unroll
            for (int r = 0; r < 4; ++r) {
                const int m = m0 + im * 16 + q * 4 + r;
                float v = acc[im][in_][r] + bb;
                v = v > 0.f ? v : 0.f;
                h0buf[(size_t)m * H + n] = (_Float16)v;
            }
        }
}

// ---------------------------------------------------------------------------
// Recurrence, round 12: 1024 threads (4 waves/SIMD), arch-VGPR pressure cut.
// Rounds 6/7 spilled ~30 regs (WRITE 121 MB): at 1024 thr the per-wave
// budget is 128 total, split 64 arch + 64 accum, and the persistent
// gb[2][4] (32 arch) overflowed the arch half. Fix: gb is DATA, not state —
//  * init: load gperm, build b0 = gperm + (pa*wc0+pb*wc1) (exact round-7
//    expression), build g1 = b0 + (cg - (pa*wc0+pb*wc1)) (exact round-7
//    t==0 update), store g1 back IN PLACE to gperm (each thread owns its
//    8 float4s; only recur reads gperm; regenerated by gemm1 every launch).
//  * step 0 peeled: MFMA C-init = b0 from registers (dies right after).
//  * steps 1..11: load bias (= g1) from gperm each step as MFMA C-init.
//    Active read footprint/XCD = 32 blocks x 128 KB = 4 MB = L2 -> L2-served
//    (~1 us/step chip-wide), unlike scratch (52 MB active, HBM thrash).
// Gates bit-identical to rounds 6/7 (verified absmax 0.0039).
// __syncthreads() fences stop the compiler re-hoisting loads into regs.
// ---------------------------------------------------------------------------
__device__ __forceinline__ float relpos16(const _Float16* s_h, const float* s_whp,
                                          int row, int j, int p) {
    const f16x8 a = *(const f16x8*)(s_h + row * 136 + p * 16);
    const f16x8 b = *(const f16x8*)(s_h + row * 136 + p * 16 + 8);
    const float* wp = s_whp + (j * 4 + (p >> 1)) * 36 + (p & 1) * 16;
    float s = 0.f;
    #pragma unroll
    for (int u = 0; u < 8; ++u)
        s += (float)a[u] * wp[u] + (float)b[u] * wp[8 + u];
    s += __shfl_down(s, 4, 64);
    s += __shfl_down(s, 2, 64);
    s += __shfl_down(s, 1, 64);
    return s;   // valid at p == 0
}

__global__ __launch_bounds__(1024)
__attribute__((amdgpu_waves_per_eu(4, 4)))
void recur_kernel(
    float* __restrict__ gperm, const _Float16* __restrict__ h0buf,
    const _Float16* __restrict__ whhf, const float* __restrict__ wc,
    const float* __restrict__ whp, const float* __restrict__ bhp,
    const float* __restrict__ lpr, float* __restrict__ out)
{
    __shared__ _Float16 s_whh[512 * 136];
    __shared__ _Float16 s_h[64 * 136];
    __shared__ float    s_p[128];
    __shared__ float    s_wc[1024];
    __shared__ float    s_whp[8 * 36];   // [j*4+part][32 floats], +4 pad
    __shared__ float    s_bhp[2];

    const int tid = threadIdx.x;
    const int m0  = blockIdx.x * 64;
    const int lane = tid & 63;
    const int w16 = tid >> 6;           // 0..15
    const int wg  = w16 & 7;            // gate-column wave index
    const int wm2 = w16 >> 3;           // m-half
    const int l15 = lane & 15, q = lane >> 4;

    // ---- staging ----
    #pragma unroll
    for (int i = 0; i < 8; ++i) {
        const int cid = tid + i * 1024;
        const int row = cid >> 4, ch = cid & 15;
        *(uint4*)(s_whh + row * 136 + ch * 8) = *(const uint4*)(whhf + row * H + ch * 8);
    }
    if (tid < 256) *(float4*)(s_wc + tid * 4)  = *(const float4*)(wc + tid * 4);
    if (tid < 64) {
        const int jp = tid >> 3;            // 0..7 = j*4+part
        const int e8 = tid & 7;             // 4-float chunk 0..7
        const int j = jp >> 2, part = jp & 3;
        *(float4*)(s_whp + jp * 36 + e8 * 4) = *(const float4*)(whp + j * H + part * 32 + e8 * 4);
    }
    if (tid < 2)   s_bhp[tid] = bhp[tid];
    if (tid < 128) s_p[tid] = lpr[(size_t)m0 * 2 + tid];
    {
        const int row = tid >> 4, ch = tid & 15;
        *(uint4*)(s_h + row * 136 + ch * 8) = *(const uint4*)(h0buf + (size_t)(m0 + row) * H + ch * 8);
    }

    f32x4 cst[2] = {};

    __syncthreads();

    // ---- init: s_p -= h0 . whp (round-3 32-wide form, tid<512) ----
    if (tid < 512) {
        const int part = tid & 3;
        const int j    = (tid >> 2) & 1;
        const int row  = tid >> 3;
        const int jp   = j * 4 + part;
        float sum = 0.f;
        #pragma unroll
        for (int u = 0; u < 4; ++u) {
            const f16x8 hv = *(const f16x8*)(s_h + row * 136 + part * 32 + u * 8);
            const float4* wp = (const float4*)(s_whp + jp * 36 + u * 8);
            const float4 w0 = wp[0], w1 = wp[1];
            sum += (float)hv[0] * w0.x + (float)hv[1] * w0.y + (float)hv[2] * w0.z + (float)hv[3] * w0.w
                 + (float)hv[4] * w1.x + (float)hv[5] * w1.y + (float)hv[6] * w1.z + (float)hv[7] * w1.w;
        }
        sum += __shfl_down(sum, 2, 64);
        sum += __shfl_down(sum, 1, 64);
        if (part == 0) s_p[row * 2 + j] -= sum;
    }
    __syncthreads();

    // ---- per-thread gperm base (float units) ----
    float* gpb = gperm + ((size_t)((m0 >> 2) + wm2 * 8 + q) * NG + wg * 16 + l15) * 4;

    // ---- build b0 (step-0 bias, regs) and g1 (t>=1 bias, stored back) ----
    f32x4 b0[2][4];
    {
        float wc0[4], wc1[4], cg[4];
        #pragma unroll
        for (int g = 0; g < 4; ++g) {
            const int n = g * H + wg * 16 + l15;
            wc0[g] = s_wc[n * 2];
            wc1[g] = s_wc[n * 2 + 1];
            cg[g]  = wc0[g] * s_bhp[0] + wc1[g] * s_bhp[1];
        }
        #pragma unroll
        for (int im = 0; im < 2; ++im)
            #pragma unroll
            for (int g = 0; g < 4; ++g) {
                const float4 v = *(const float4*)(gpb + im * 8192 + g * 512);
                b0[im][g] = f32x4{v.x, v.y, v.z, v.w};
            }
        #pragma unroll
        for (int im = 0; im < 2; ++im)
            #pragma unroll
            for (int r = 0; r < 4; ++r) {
                const int mrow = wm2 * 32 + im * 16 + q * 4 + r;
                const float pa = s_p[mrow * 2], pb = s_p[mrow * 2 + 1];
                #pragma unroll
                for (int g = 0; g < 4; ++g)
                    b0[im][g][r] += pa * wc0[g] + pb * wc1[g];
            }
        #pragma unroll
        for (int im = 0; im < 2; ++im) {
            f32x4 g1[4];
            #pragma unroll
            for (int g = 0; g < 4; ++g) g1[g] = b0[im][g];
            #pragma unroll
            for (int r = 0; r < 4; ++r) {
                const int mrow = wm2 * 32 + im * 16 + q * 4 + r;
                const float pa = s_p[mrow * 2], pb = s_p[mrow * 2 + 1];
                #pragma unroll
                for (int g = 0; g < 4; ++g)
                    g1[g][r] += cg[g] - (pa * wc0[g] + pb * wc1[g]);
            }
            #pragma unroll
            for (int g = 0; g < 4; ++g) {
                float4 v;
                v.x = g1[g][0]; v.y = g1[g][1]; v.z = g1[g][2]; v.w = g1[g][3];
                *(float4*)(gpb + im * 8192 + g * 512) = v;
            }
        }
    }

    const int rp_p = tid & 7, rp_j = (tid >> 3) & 1, rp_r = tid >> 4;  // rows 0..63

    // ---- step 0 (peeled): MFMA with C = b0 from registers ----
    {
        f32x4 acc[2][4];
        #pragma unroll
        for (int kt = 0; kt < 4; ++kt) {
            f16x8 af[2];
            #pragma unroll
            for (int im = 0; im < 2; ++im)
                af[im] = *(const f16x8*)(s_h + (wm2 * 32 + im * 16 + l15) * 136 + kt * 32 + q * 8);
            #pragma unroll
            for (int g = 0; g < 4; ++g) {
                const f16x8 bf = *(const f16x8*)(s_whh + (g * H + wg * 16 + l15) * 136 + kt * 32 + q * 8);
                #pragma unroll
                for (int im = 0; im < 2; ++im)
                    acc[im][g] = __builtin_amdgcn_mfma_f32_16x16x32_f16(
                        af[im], bf, (kt == 0) ? b0[im][g] : acc[im][g], 0, 0, 0);
            }
        }
        __syncthreads();
        #pragma unroll
        for (int im = 0; im < 2; ++im) {
            #pragma unroll
            for (int r = 0; r < 4; ++r) {
                const int mrow = wm2 * 32 + im * 16 + q * 4 + r;
                const float cc = sigf(acc[im][1][r]) * cst[im][r]
                               + sigf(acc[im][0][r]) * tanhfast(acc[im][2][r]);
                cst[im][r] = cc;
                const float hh = sigf(acc[im][3][r]) * tanhfast(cc);
                s_h[mrow * 136 + wg * 16 + l15] = (_Float16)hh;
            }
        }
        __syncthreads();
    }

    // ---- steps 1..11: bias reloaded from gperm (L2) each step ----
    for (int t = 1; t < SEQLEN; ++t) {
        f32x4 bias[2][4];
        #pragma unroll
        for (int im = 0; im < 2; ++im)
            #pragma unroll
            for (int g = 0; g < 4; ++g) {
                const float4 v = *(const float4*)(gpb + im * 8192 + g * 512);
                bias[im][g] = f32x4{v.x, v.y, v.z, v.w};
            }
        f32x4 acc[2][4];
        #pragma unroll
        for (int kt = 0; kt < 4; ++kt) {
            f16x8 af[2];
            #pragma unroll
            for (int im = 0; im < 2; ++im)
                af[im] = *(const f16x8*)(s_h + (wm2 * 32 + im * 16 + l15) * 136 + kt * 32 + q * 8);
            #pragma unroll
            for (int g = 0; g < 4; ++g) {
                const f16x8 bf = *(const f16x8*)(s_whh + (g * H + wg * 16 + l15) * 136 + kt * 32 + q * 8);
                #pragma unroll
                for (int im = 0; im < 2; ++im)
                    acc[im][g] = __builtin_amdgcn_mfma_f32_16x16x32_f16(
                        af[im], bf, (kt == 0) ? bias[im][g] : acc[im][g], 0, 0, 0);
            }
        }
        {
            const float sm = relpos16(s_h, s_whp, rp_r, rp_j, rp_p);
            if (rp_p == 0)
                out[(size_t)(t - 1) * (BATCH * 2) + (size_t)(m0 + rp_r) * 2 + rp_j]
                    = sm + s_bhp[rp_j];
        }
        __syncthreads();

        #pragma unroll
        for (int im = 0; im < 2; ++im) {
            #pragma unroll
            for (int r = 0; r < 4; ++r) {
                const int mrow = wm2 * 32 + im * 16 + q * 4 + r;
                const float cc = sigf(acc[im][1][r]) * cst[im][r]
                               + sigf(acc[im][0][r]) * tanhfast(acc[im][2][r]);
                cst[im][r] = cc;
                const float hh = sigf(acc[im][3][r]) * tanhfast(cc);
                s_h[mrow * 136 + wg * 16 + l15] = (_Float16)hh;
            }
        }
        __syncthreads();
    }

    // ---- final rel-pos (t = SEQLEN-1) ----
    {
        const float sm = relpos16(s_h, s_whp, rp_r, rp_j, rp_p);
        if (rp_p == 0)
            out[(size_t)(SEQLEN - 1) * (BATCH * 2) + (size_t)(m0 + rp_r) * 2 + rp_j]
                = sm + s_bhp[rp_j];
    }
}

// ---------------------------------------------------------------------------
extern "C" void kernel_launch(void* const* d_in, const int* in_sizes, int n_in,
                              void* d_out, int out_size, void* d_ws, size_t ws_size,
                              hipStream_t stream)
{
    const float* last_pos_rel = (const float*)d_in[1];
    const float* enc          = (const float*)d_in[2];
    const float* zin          = (const float*)d_in[3];
    const float* W_ih         = (const float*)d_in[5];
    const float* W_hh         = (const float*)d_in[6];
    const float* b_ih         = (const float*)d_in[7];
    const float* b_hh         = (const float*)d_in[8];
    const float* W1           = (const float*)d_in[9];
    const float* b1           = (const float*)d_in[10];
    const float* W2           = (const float*)d_in[11];
    const float* b2           = (const float*)d_in[12];
    const float* W_sp         = (const float*)d_in[13];
    const float* b_sp         = (const float*)d_in[14];
    const float* W_hp         = (const float*)d_in[15];
    const float* b_hp         = (const float*)d_in[16];
    float* out = (float*)d_out;

    char* ws = (char*)d_ws;
    const bool big = (ws_size >= B_TOTAL);

    _Float16* wcat  = (_Float16*)(ws + (big ? B_WCAT_OFF  : S_WCAT_OFF));
    _Float16* w2h   = (_Float16*)(ws + (big ? B_W2H_OFF   : S_W2H_OFF));
    _Float16* whhf  = (_Float16*)(ws + (big ? B_WHHF_OFF  : S_WHHF_OFF));
    float*    wc    = (float*)(ws + (big ? B_WC_OFF    : S_WC_OFF));
    float*    bias2 = (float*)(ws + (big ? B_BIAS2_OFF : S_BIAS2_OFF));
    _Float16* t1    = (_Float16*)(ws + (big ? B_T1_OFF : S_T1_OFF));
    float*    gperm = (float*)(ws + (big ? B_GP_OFF : S_GP_OFF));
    _Float16* h0b   = (_Float16*)(ws + (big ? B_H0_OFF : S_H0_OFF));
    _Float16* zx16  = (_Float16*)(ws + B_ZX16_OFF);

    prep_kernel<<<dim3(1926), 256, 0, stream>>>(W_ih, W_hh, b_ih, b_hh, W1, W2, W_sp, b_sp,
                                                W_hp, big ? KP : ZX, wcat, w2h, whhf, wc, bias2);
    if (big) {
        zxcast_kernel<<<dim3(17408), 256, 0, stream>>>(enc, zin, zx16);
        gemm1_big_kernel<<<dim3(768), 512, 0, stream>>>(zx16, wcat, b1, bias2, t1, gperm);
    } else {
        gemm1_small_kernel<<<dim3(3072), 256, 0, stream>>>(enc, zin, wcat, b1, bias2, t1, gperm);
    }
    gemm2_kernel<<<dim3(512), 256, 0, stream>>>(t1, w2h, b2, h0b);
    recur_kernel<<<dim3(512), 1024, 0, stream>>>(gperm, h0b, whhf, wc, W_hp, b_hp,
                                                 last_pos_rel, out);
}

// Round 9
// 478.943 us; speedup vs baseline: 1.1103x; 1.0742x over previous
//
#include <hip/hip_runtime.h>

// ---------- problem constants ----------
#define BATCH   32768
#define SEQLEN  12
#define EMB     64
#define H       128
#define MLP     1024
#define Z       32
#define ZX      1056      // MLP + Z
#define KP      1088      // ZX padded to 17*64 (big path)
#define NG      512       // 4*H gates

typedef _Float16 f16x8 __attribute__((ext_vector_type(8)));
typedef float    f32x4 __attribute__((ext_vector_type(4)));

// ---------- workspace layouts ----------
// small path (ws < 217,651,200): round-3 layout, total 146,249,728
#define S_WCAT_OFF   0u
#define S_W2H_OFF    3244032u
#define S_WHHF_OFF   3506176u
#define S_WC_OFF     3637248u
#define S_BIAS2_OFF  3641344u
#define S_T1_OFF     3643392u
#define S_GP_OFF     70752256u
#define S_H0_OFF     137861120u
// big path: wcat stride 1088 + zx16 buffer, total 217,651,200
#define B_WCAT_OFF   0u           // 1536*1088*2 = 3,342,336
#define B_W2H_OFF    3342336u
#define B_WHHF_OFF   3604480u
#define B_WC_OFF     3735552u
#define B_BIAS2_OFF  3739648u
#define B_T1_OFF     3741696u
#define B_GP_OFF     70850560u
#define B_H0_OFF     137959424u
#define B_ZX16_OFF   146348032u
#define B_TOTAL      217651200ull

__device__ __forceinline__ float sigf(float x) {
    return __builtin_amdgcn_rcpf(1.0f + __expf(-x));
}
__device__ __forceinline__ float tanhfast(float x) {
    return 2.0f * __builtin_amdgcn_rcpf(1.0f + __expf(-2.0f * x)) - 1.0f;
}

// async global->LDS, 16B per lane. LDS dest = wave-uniform base + lane*16.
__device__ __forceinline__ void gload16(const void* g, void* l) {
    __builtin_amdgcn_global_load_lds(
        (const __attribute__((address_space(1))) unsigned int*)(unsigned long long)(uintptr_t)g,
        (__attribute__((address_space(3))) unsigned int*)(unsigned int)(uintptr_t)l,
        16, 0, 0);
}

// ---------------------------------------------------------------------------
// prep: pack weights fp16 (wcat stride = cs, zero-padded past 1056),
// fold biases, fold rel_pos feedback into W_hh.
// ---------------------------------------------------------------------------
__global__ __launch_bounds__(256) void prep_kernel(
    const float* __restrict__ W_ih, const float* __restrict__ W_hh_in,
    const float* __restrict__ b_ih, const float* __restrict__ b_hh,
    const float* __restrict__ W1,   const float* __restrict__ W2,
    const float* __restrict__ W_sp, const float* __restrict__ b_sp,
    const float* __restrict__ W_hp, int cs,
    _Float16* __restrict__ wcat, _Float16* __restrict__ w2h,
    _Float16* __restrict__ whhf, float* __restrict__ wc, float* __restrict__ bias2)
{
    const int bid = blockIdx.x;
    const int tid = threadIdx.x;
    if (bid < 1536) {
        const float* src = (bid < 1024) ? (W1 + (size_t)bid * ZX)
                                        : (W_ih + (size_t)(bid - 1024) * 1120);
        _Float16* dst = wcat + (size_t)bid * cs;
        for (int k = tid; k < cs; k += 256)
            dst[k] = (k < ZX) ? (_Float16)src[k] : (_Float16)0.f;
    } else if (bid < 1664) {
        const int n = bid - 1536;
        for (int k = tid; k < MLP; k += 256)
            w2h[n * MLP + k] = (_Float16)W2[n * MLP + k];
    } else if (bid < 1920) {
        const int n = (bid - 1664) * 2 + (tid >> 7);
        const int k = tid & 127;
        float wc0 = 0.f, wc1 = 0.f;
        for (int e = 0; e < EMB; ++e) {
            const float we = W_ih[(size_t)n * 1120 + ZX + e];
            wc0 += we * W_sp[e * 2];
            wc1 += we * W_sp[e * 2 + 1];
        }
        whhf[n * H + k] = (_Float16)(W_hh_in[n * H + k] + wc0 * W_hp[k] + wc1 * W_hp[H + k]);
    } else {
        const int t = (bid - 1920) * 256 + tid;
        if (t < 1024) {
            const int n = t >> 1, j = t & 1;
            float s = 0.f;
            for (int e = 0; e < EMB; ++e)
                s += W_ih[(size_t)n * 1120 + ZX + e] * W_sp[e * 2 + j];
            wc[t] = s;
        } else if (t < 1536) {
            const int n = t - 1024;
            float s = b_ih[n] + b_hh[n];
            for (int e = 0; e < EMB; ++e)
                s += W_ih[(size_t)n * 1120 + ZX + e] * b_sp[e];
            bias2[n] = s;
        }
    }
}

// ---------------------------------------------------------------------------
// zxcast (big path): zx16[32768][1088] = fp16([enc | z | zeros])
// 8 halfs per thread; grid = 4456448/256 = 17408 blocks.
// ---------------------------------------------------------------------------
__global__ __launch_bounds__(256) void zxcast_kernel(
    const float* __restrict__ enc, const float* __restrict__ zin,
    _Float16* __restrict__ zx16)
{
    const int gid = blockIdx.x * 256 + threadIdx.x;
    if (gid < 4194304) {                       // enc: 128 chunks/row
        const int row = gid >> 7, cw = gid & 127;
        const float4* s = (const float4*)(enc + (size_t)row * MLP + cw * 8);
        const float4 f0 = s[0], f1 = s[1];
        f16x8 v = {(_Float16)f0.x, (_Float16)f0.y, (_Float16)f0.z, (_Float16)f0.w,
                   (_Float16)f1.x, (_Float16)f1.y, (_Float16)f1.z, (_Float16)f1.w};
        *(f16x8*)(zx16 + (size_t)row * KP + cw * 8) = v;
    } else if (gid < 4325376) {                // z: 4 chunks/row
        const int g2 = gid - 4194304;
        const int row = g2 >> 2, cw = g2 & 3;
        const float4* s = (const float4*)(zin + (size_t)row * Z + cw * 8);
        const float4 f0 = s[0], f1 = s[1];
        f16x8 v = {(_Float16)f0.x, (_Float16)f0.y, (_Float16)f0.z, (_Float16)f0.w,
                   (_Float16)f1.x, (_Float16)f1.y, (_Float16)f1.z, (_Float16)f1.w};
        *(f16x8*)(zx16 + (size_t)row * KP + MLP + cw * 8) = v;
    } else {                                   // pad: 4 chunks/row of zeros
        const int g2 = gid - 4325376;
        const int row = g2 >> 2, cw = g2 & 3;
        f16x8 v = {};
        *(f16x8*)(zx16 + (size_t)row * KP + ZX + cw * 8) = v;
    }
}

// ---------------------------------------------------------------------------
// GEMM1 big path, round 5: 256x256 tile, BK=64, 512 thr (8 waves, 2M x 4N),
// 128 KB double-buffered LDS, 4-phase-per-K-tile schedule with counted
// vmcnt (T3+T4) + s_setprio around MFMA clusters (T5). Verified round 1.
// ---------------------------------------------------------------------------
__global__ __launch_bounds__(512, 2) void gemm1_big_kernel(
    const _Float16* __restrict__ zx16, const _Float16* __restrict__ wcat,
    const float* __restrict__ bias1, const float* __restrict__ bias2g,
    _Float16* __restrict__ t1, float* __restrict__ gperm)
{
    __shared__ _Float16 s_a[2][256 * 64];   // 64 KB
    __shared__ _Float16 s_b[2][256 * 64];   // 64 KB

    const int tid = threadIdx.x;
    const int b   = blockIdx.x;
    const int swz = (b & 7) * 96 + (b >> 3);
    const int mt  = swz / 6, nt = swz % 6;
    const int m0  = mt * 256, n0 = nt * 256;

    const int lane = tid & 63, wv = tid >> 6;
    const int wm   = wv >> 2,  wn = wv & 3;
    const int l15  = lane & 15, q = lane >> 4;

    const int rowS = tid >> 3;
    const int chS  = (tid & 7) ^ (rowS & 7);

    const _Float16* gA = zx16 + (size_t)(m0 + rowS) * KP + chS * 8;
    const _Float16* gB = wcat + (size_t)(n0 + rowS) * KP + chS * 8;
    const size_t rstep = (size_t)64 * KP;

    const int ph0  = q ^ (l15 & 7);           // k-slice 0
    const int ph1  = (4 + q) ^ (l15 & 7);     // k-slice 1
    const int aof0 = (wm * 128 + l15) * 64 + ph0 * 8;
    const int aof1 = (wm * 128 + l15) * 64 + ph1 * 8;
    const int bof0 = (wn * 64 + l15) * 64 + ph0 * 8;
    const int bof1 = (wn * 64 + l15) * 64 + ph1 * 8;

    f32x4 acc[8][4] = {};

    // prologue: stage K-tile 0 into buffer 0 (8 loads)
    {
        _Float16* dA = &s_a[0][0] + wv * 512;
        _Float16* dB = &s_b[0][0] + wv * 512;
        #pragma unroll
        for (int j = 0; j < 4; ++j) gload16(gA + j * rstep, dA + j * 4096);
        #pragma unroll
        for (int j = 0; j < 4; ++j) gload16(gB + j * rstep, dB + j * 4096);
    }

    #pragma unroll 2
    for (int kt = 0; kt < 16; ++kt) {
        const int cur = kt & 1;
        const _Float16* sA = &s_a[cur][0];
        const _Float16* sB = &s_b[cur][0];
        _Float16* dA = &s_a[cur ^ 1][0] + wv * 512;
        _Float16* dB = &s_b[cur ^ 1][0] + wv * 512;
        const _Float16* gA1 = gA + (kt + 1) * 64;
        const _Float16* gB1 = gB + (kt + 1) * 64;

        f16x8 af[4], bf[4];

        // ---- PH0: ks0/qm0; stage A-half0 of t+1; counted wait for tile t
        gload16(gA1,         dA);
        gload16(gA1 + rstep, dA + 4096);
        asm volatile("s_waitcnt vmcnt(2)\n\ts_barrier" ::: "memory");
        #pragma unroll
        for (int i = 0; i < 4; ++i) af[i] = *(const f16x8*)(sA + aof0 + i * 1024);
        #pragma unroll
        for (int i = 0; i < 4; ++i) bf[i] = *(const f16x8*)(sB + bof0 + i * 1024);
        __builtin_amdgcn_s_setprio(1);
        #pragma unroll
        for (int n_ = 0; n_ < 4; ++n_)
            #pragma unroll
            for (int m_ = 0; m_ < 4; ++m_)
                acc[m_][n_] = __builtin_amdgcn_mfma_f32_16x16x32_f16(af[m_], bf[n_], acc[m_][n_], 0, 0, 0);
        __builtin_amdgcn_s_setprio(0);
        asm volatile("s_barrier" ::: "memory");

        // ---- PH1: ks0/qm1; stage A-half1 of t+1 (bf ks0 reused in regs)
        gload16(gA1 + 2 * rstep, dA + 8192);
        gload16(gA1 + 3 * rstep, dA + 12288);
        #pragma unroll
        for (int i = 0; i < 4; ++i) af[i] = *(const f16x8*)(sA + aof0 + 4096 + i * 1024);
        asm volatile("s_barrier" ::: "memory");
        __builtin_amdgcn_s_setprio(1);
        #pragma unroll
        for (int n_ = 0; n_ < 4; ++n_)
            #pragma unroll
            for (int m_ = 0; m_ < 4; ++m_)
                acc[4 + m_][n_] = __builtin_amdgcn_mfma_f32_16x16x32_f16(af[m_], bf[n_], acc[4 + m_][n_], 0, 0, 0);
        __builtin_amdgcn_s_setprio(0);
        asm volatile("s_barrier" ::: "memory");

        // ---- PH2: ks1/qm0; stage B-half0 of t+1
        gload16(gB1,         dB);
        gload16(gB1 + rstep, dB + 4096);
        #pragma unroll
        for (int i = 0; i < 4; ++i) af[i] = *(const f16x8*)(sA + aof1 + i * 1024);
        #pragma unroll
        for (int i = 0; i < 4; ++i) bf[i] = *(const f16x8*)(sB + bof1 + i * 1024);
        asm volatile("s_barrier" ::: "memory");
        __builtin_amdgcn_s_setprio(1);
        #pragma unroll
        for (int n_ = 0; n_ < 4; ++n_)
            #pragma unroll
            for (int m_ = 0; m_ < 4; ++m_)
                acc[m_][n_] = __builtin_amdgcn_mfma_f32_16x16x32_f16(af[m_], bf[n_], acc[m_][n_], 0, 0, 0);
        __builtin_amdgcn_s_setprio(0);
        asm volatile("s_barrier" ::: "memory");

        // ---- PH3: ks1/qm1; stage B-half1 of t+1
        gload16(gB1 + 2 * rstep, dB + 8192);
        gload16(gB1 + 3 * rstep, dB + 12288);
        #pragma unroll
        for (int i = 0; i < 4; ++i) af[i] = *(const f16x8*)(sA + aof1 + 4096 + i * 1024);
        asm volatile("s_barrier" ::: "memory");
        __builtin_amdgcn_s_setprio(1);
        #pragma unroll
        for (int n_ = 0; n_ < 4; ++n_)
            #pragma unroll
            for (int m_ = 0; m_ < 4; ++m_)
                acc[4 + m_][n_] = __builtin_amdgcn_mfma_f32_16x16x32_f16(af[m_], bf[n_], acc[4 + m_][n_], 0, 0, 0);
        __builtin_amdgcn_s_setprio(0);
        asm volatile("s_barrier" ::: "memory");
    }

    // ---- tail: K-tile 16 (buffer 0), full drain allowed (no more stages)
    {
        const _Float16* sA = &s_a[0][0];
        const _Float16* sB = &s_b[0][0];
        asm volatile("s_waitcnt vmcnt(0)\n\ts_barrier" ::: "memory");
        f16x8 af[4], bf[4];
        #pragma unroll
        for (int i = 0; i < 4; ++i) af[i] = *(const f16x8*)(sA + aof0 + i * 1024);
        #pragma unroll
        for (int i = 0; i < 4; ++i) bf[i] = *(const f16x8*)(sB + bof0 + i * 1024);
        __builtin_amdgcn_s_setprio(1);
        #pragma unroll
        for (int n_ = 0; n_ < 4; ++n_)
            #pragma unroll
            for (int m_ = 0; m_ < 4; ++m_)
                acc[m_][n_] = __builtin_amdgcn_mfma_f32_16x16x32_f16(af[m_], bf[n_], acc[m_][n_], 0, 0, 0);
        #pragma unroll
        for (int i = 0; i < 4; ++i) af[i] = *(const f16x8*)(sA + aof0 + 4096 + i * 1024);
        #pragma unroll
        for (int n_ = 0; n_ < 4; ++n_)
            #pragma unroll
            for (int m_ = 0; m_ < 4; ++m_)
                acc[4 + m_][n_] = __builtin_amdgcn_mfma_f32_16x16x32_f16(af[m_], bf[n_], acc[4 + m_][n_], 0, 0, 0);
        #pragma unroll
        for (int i = 0; i < 4; ++i) af[i] = *(const f16x8*)(sA + aof1 + i * 1024);
        #pragma unroll
        for (int i = 0; i < 4; ++i) bf[i] = *(const f16x8*)(sB + bof1 + i * 1024);
        #pragma unroll
        for (int n_ = 0; n_ < 4; ++n_)
            #pragma unroll
            for (int m_ = 0; m_ < 4; ++m_)
                acc[m_][n_] = __builtin_amdgcn_mfma_f32_16x16x32_f16(af[m_], bf[n_], acc[m_][n_], 0, 0, 0);
        #pragma unroll
        for (int i = 0; i < 4; ++i) af[i] = *(const f16x8*)(sA + aof1 + 4096 + i * 1024);
        #pragma unroll
        for (int n_ = 0; n_ < 4; ++n_)
            #pragma unroll
            for (int m_ = 0; m_ < 4; ++m_)
                acc[4 + m_][n_] = __builtin_amdgcn_mfma_f32_16x16x32_f16(af[m_], bf[n_], acc[4 + m_][n_], 0, 0, 0);
        __builtin_amdgcn_s_setprio(0);
    }

    // ---- epilogue: nt<4 -> t1 (relu, fp16); nt>=4 -> gperm (fp32, permuted)
    if (nt < 4) {
        #pragma unroll
        for (int im = 0; im < 8; ++im)
            #pragma unroll
            for (int in_ = 0; in_ < 4; ++in_) {
                const int n = n0 + wn * 64 + in_ * 16 + l15;
                const float bb = bias1[n];
                const int mbase = m0 + wm * 128 + im * 16 + q * 4;
                #pragma unroll
                for (int r = 0; r < 4; ++r) {
                    float v = acc[im][in_][r] + bb;
                    v = v > 0.f ? v : 0.f;
                    t1[(size_t)(mbase + r) * MLP + n] = (_Float16)v;
                }
            }
    } else {
        #pragma unroll
        for (int im = 0; im < 8; ++im)
            #pragma unroll
            for (int in_ = 0; in_ < 4; ++in_) {
                const int n = (n0 - 1024) + wn * 64 + in_ * 16 + l15;
                const float bb = bias2g[n];
                const int m4 = (m0 + wm * 128 + im * 16 + q * 4) >> 2;
                float4 v;
                v.x = acc[im][in_][0] + bb;
                v.y = acc[im][in_][1] + bb;
                v.z = acc[im][in_][2] + bb;
                v.w = acc[im][in_][3] + bb;
                *(float4*)(gperm + ((size_t)m4 * NG + n) * 4) = v;
            }
    }
}

// ---------------------------------------------------------------------------
// GEMM1 small path: round-3 kernel verbatim (fp32 A, BK=32, stride 1056).
// ---------------------------------------------------------------------------
__global__ __launch_bounds__(256) void gemm1_small_kernel(
    const float* __restrict__ enc, const float* __restrict__ zin,
    const _Float16* __restrict__ wcat,
    const float* __restrict__ bias1, const float* __restrict__ bias2g,
    _Float16* __restrict__ t1, float* __restrict__ gperm)
{
    __shared__ float    s_a[128 * 32];
    __shared__ _Float16 s_b[128 * 32];

    const int tid = threadIdx.x;
    const int b = blockIdx.x;
    const int x = b & 7, s = b >> 3;
    const int mt = x * 32 + s / 12;
    const int bn = s % 12;
    const int m0 = mt * 128;

    const int lane = tid & 63, wv = tid >> 6;
    const int wm = wv >> 1, wn = wv & 1;
    const int l15 = lane & 15, q = lane >> 4;

    const int rowA = tid >> 3;
    const int chA  = (tid & 7) ^ ((tid >> 3) & 7);
    const int rowB = tid >> 2;
    const int chB  = (tid & 3) ^ ((tid >> 3) & 3);

    const int ca0 = (2 * q) ^ (l15 & 7);
    const int cb  = q ^ ((l15 >> 1) & 3);

    f32x4 acc[4][4] = {};

    for (int kt = 0; kt < 33; ++kt) {
        const float* abase;
        size_t astride;
        if (kt < 32) { abase = enc + (size_t)m0 * MLP + kt * 32; astride = MLP; }
        else         { abase = zin + (size_t)m0 * Z;             astride = Z;   }

        __syncthreads();
        #pragma unroll
        for (int i = 0; i < 4; ++i)
            gload16(abase + (size_t)(i * 32 + rowA) * astride + chA * 4,
                    s_a + i * 1024 + wv * 256);
        #pragma unroll
        for (int i = 0; i < 2; ++i)
            gload16(wcat + (size_t)(bn * 128 + i * 64 + rowB) * ZX + kt * 32 + chB * 8,
                    s_b + i * 2048 + wv * 512);
        __syncthreads();

        f16x8 af[4];
        #pragma unroll
        for (int im = 0; im < 4; ++im) {
            const float* ap = s_a + (wm * 64 + im * 16 + l15) * 32;
            const float4 f0 = *(const float4*)(ap + ca0 * 4);
            const float4 f1 = *(const float4*)(ap + (ca0 ^ 1) * 4);
            af[im] = f16x8{(_Float16)f0.x, (_Float16)f0.y, (_Float16)f0.z, (_Float16)f0.w,
                           (_Float16)f1.x, (_Float16)f1.y, (_Float16)f1.z, (_Float16)f1.w};
        }
        #pragma unroll
        for (int in_ = 0; in_ < 4; ++in_) {
            const f16x8 bf = *(const f16x8*)(s_b + (wn * 64 + in_ * 16 + l15) * 32 + cb * 8);
            #pragma unroll
            for (int im = 0; im < 4; ++im)
                acc[im][in_] = __builtin_amdgcn_mfma_f32_16x16x32_f16(af[im], bf, acc[im][in_], 0, 0, 0);
        }
    }

    if (bn < 8) {
        #pragma unroll
        for (int im = 0; im < 4; ++im)
            #pragma unroll
            for (int in_ = 0; in_ < 4; ++in_) {
                const int n = bn * 128 + wn * 64 + in_ * 16 + l15;
                const float bb = bias1[n];
                #pragma unroll
                for (int r = 0; r < 4; ++r) {
                    const int m = m0 + wm * 64 + im * 16 + q * 4 + r;
                    float v = acc[im][in_][r] + bb;
                    v = v > 0.f ? v : 0.f;
                    t1[(size_t)m * MLP + n] = (_Float16)v;
                }
            }
    } else {
        #pragma unroll
        for (int im = 0; im < 4; ++im)
            #pragma unroll
            for (int in_ = 0; in_ < 4; ++in_) {
                const int n = (bn - 8) * 128 + wn * 64 + in_ * 16 + l15;
                const float bb = bias2g[n];
                const int m4 = (m0 + wm * 64 + im * 16 + q * 4) >> 2;
                float4 v;
                v.x = acc[im][in_][0] + bb;
                v.y = acc[im][in_][1] + bb;
                v.z = acc[im][in_][2] + bb;
                v.w = acc[im][in_][3] + bb;
                *(float4*)(gperm + ((size_t)m4 * NG + n) * 4) = v;
            }
    }
}

// ---------------------------------------------------------------------------
// GEMM2 round 13: counted-vmcnt double-buffer (T3/T4 minimum 2-phase).
// Same addresses/swizzles/MFMA order as the verified v2 kernel — only load
// timing changes: stage(kt+1) is issued BEFORE the barrier that releases
// compute(kt), with s_waitcnt vmcnt(3) (the 3 new loads stay in flight)
// instead of a vmcnt(0) drain. Race audit: stage(kt+1) writes buf[(kt+1)&1],
// last read during compute(kt-1), fenced by iter kt-1's trailing barrier;
// the leading barrier (after each wave's vmcnt) guarantees ALL waves' tile-kt
// loads landed. Identical shape to gemm1_big's verified PH0 pattern.
// ---------------------------------------------------------------------------
__global__ __launch_bounds__(256) void gemm2_kernel(
    const _Float16* __restrict__ t1, const _Float16* __restrict__ w2h,
    const float* __restrict__ b2, _Float16* __restrict__ h0buf)
{
    __shared__ _Float16 s_a[2][64 * 32];    // 2 x 4 KB
    __shared__ _Float16 s_b[2][128 * 32];   // 2 x 8 KB

    const int tid = threadIdx.x;
    const int m0  = blockIdx.x * 64;
    const int lane = tid & 63, wv = tid >> 6;
    const int l15 = lane & 15, q = lane >> 4;

    // staging: slot P -> row=P>>2, pch=P&3, logical c=(pch^row^(row>>2))&3
    const int rowS = tid >> 2;
    const int chS  = ((tid & 3) ^ (tid >> 2) ^ (tid >> 4)) & 3;
    // frag phys chunk: (q ^ l15 ^ (l15>>2)) & 3
    const int phF  = (q ^ l15 ^ (l15 >> 2)) & 3;

    const int rowB0 = rowS, rowB1 = 64 + rowS;
    const int cB0 = ((tid & 3) ^ rowB0 ^ (rowB0 >> 2)) & 3;
    const int cB1 = ((tid & 3) ^ rowB1 ^ (rowB1 >> 2)) & 3;

    const _Float16* gA  = t1  + (size_t)(m0 + rowS) * MLP + chS * 8;
    const _Float16* gB0 = w2h + (size_t)rowB0 * MLP + cB0 * 8;
    const _Float16* gB1 = w2h + (size_t)rowB1 * MLP + cB1 * 8;

    f32x4 acc[4][2] = {};

    // prologue: stage kt=0 into buffer 0 (3 loads/thread)
    gload16(gA,  &s_a[0][0] + wv * 512);
    gload16(gB0, &s_b[0][0] + wv * 512);
    gload16(gB1, &s_b[0][0] + 2048 + wv * 512);

    for (int kt = 0; kt < 32; ++kt) {
        const int cur = kt & 1;
        if (kt < 31) {
            const int nxt = cur ^ 1;
            gload16(gA  + (kt + 1) * 32, &s_a[nxt][0] + wv * 512);
            gload16(gB0 + (kt + 1) * 32, &s_b[nxt][0] + wv * 512);
            gload16(gB1 + (kt + 1) * 32, &s_b[nxt][0] + 2048 + wv * 512);
            asm volatile("s_waitcnt vmcnt(3)\n\ts_barrier" ::: "memory");
        } else {
            asm volatile("s_waitcnt vmcnt(0)\n\ts_barrier" ::: "memory");
        }

        f16x8 af[4];
        #pragma unroll
        for (int im = 0; im < 4; ++im)
            af[im] = *(const f16x8*)(&s_a[cur][0] + (im * 16 + l15) * 32 + phF * 8);
        #pragma unroll
        for (int in_ = 0; in_ < 2; ++in_) {
            const f16x8 bf = *(const f16x8*)(&s_b[cur][0] + (wv * 32 + in_ * 16 + l15) * 32 + phF * 8);
            #pragma unroll
            for (int im = 0; im < 4; ++im)
                acc[im][in_] = __builtin_amdgcn_mfma_f32_16x16x32_f16(af[im], bf, acc[im][in_], 0, 0, 0);
        }
        asm volatile("s_barrier" ::: "memory");
    }

    #pragma unroll
    for (int im = 0; im < 4; ++im)
        #pragma unroll
        for (int in_ = 0; in_ < 2; ++in_) {
            const int n = wv * 32 + in_ * 16 + l15;
            const float bb = b2[n];
            #pragma unroll
            for (int r = 0; r < 4; ++r) {
                const int m = m0 + im * 16 + q * 4 + r;
                float v = acc[im][in_][r] + bb;
                v = v > 0.f ? v : 0.f;
                h0buf[(size_t)m * H + n] = (_Float16)v;
            }
        }
}

// ---------------------------------------------------------------------------
// Recurrence: round-1 verified kernel verbatim (132.5 us, absmax 0.0039).
// Occupancy/dual-pipe/bias-reload variants (rounds 3-8) all measured
// 137-170 us — the serial 24-barrier x 12-step chain is the floor for this
// structure; this is the best measured configuration.
// ---------------------------------------------------------------------------
__global__ __launch_bounds__(512) void recur_kernel(
    const float* __restrict__ gperm, const _Float16* __restrict__ h0buf,
    const _Float16* __restrict__ whhf, const float* __restrict__ wc,
    const float* __restrict__ whp, const float* __restrict__ bhp,
    const float* __restrict__ lpr, float* __restrict__ out)
{
    __shared__ _Float16 s_whh[512 * 136];
    __shared__ _Float16 s_h[64 * 136];
    __shared__ float    s_p[128];
    __shared__ float    s_wc[1024];
    __shared__ float    s_whp[256];
    __shared__ float    s_bhp[2];

    const int tid = threadIdx.x;
    const int m0  = blockIdx.x * 64;
    const int lane = tid & 63, w = tid >> 6;
    const int l15 = lane & 15, q = lane >> 4;

    #pragma unroll
    for (int i = 0; i < 16; ++i) {
        const int cid = tid + i * 512;
        const int row = cid >> 4, ch = cid & 15;
        *(uint4*)(s_whh + row * 136 + ch * 8) = *(const uint4*)(whhf + row * H + ch * 8);
    }
    if (tid < 256) *(float4*)(s_wc + tid * 4)  = *(const float4*)(wc + tid * 4);
    if (tid < 64)  *(float4*)(s_whp + tid * 4) = *(const float4*)(whp + tid * 4);
    if (tid < 2)   s_bhp[tid] = bhp[tid];
    if (tid < 128) s_p[tid] = lpr[(size_t)m0 * 2 + tid];
    {
        const int row = tid >> 3, ch = tid & 7;
        *(uint4*)(s_h + row * 136 + ch * 16)     = *(const uint4*)(h0buf + (size_t)(m0 + row) * H + ch * 16);
        *(uint4*)(s_h + row * 136 + ch * 16 + 8) = *(const uint4*)(h0buf + (size_t)(m0 + row) * H + ch * 16 + 8);
    }

    f32x4 gb[4][4];
    #pragma unroll
    for (int im = 0; im < 4; ++im) {
        const int m4 = (m0 >> 2) + im * 4 + q;
        #pragma unroll
        for (int g = 0; g < 4; ++g) {
            const float4 v = *(const float4*)(gperm + ((size_t)m4 * NG + g * H + w * 16 + l15) * 4);
            gb[im][g] = f32x4{v.x, v.y, v.z, v.w};
        }
    }

    f32x4 cst[4] = {};

    __syncthreads();

    {
        const int part = tid & 3;
        const int j    = (tid >> 2) & 1;
        const int row  = tid >> 3;
        float sum = 0.f;
        #pragma unroll
        for (int u = 0; u < 4; ++u) {
            const f16x8 hv = *(const f16x8*)(s_h + row * 136 + part * 32 + u * 8);
            const float4* wp = (const float4*)(s_whp + j * H + part * 32 + u * 8);
            const float4 w0 = wp[0], w1 = wp[1];
            sum += (float)hv[0] * w0.x + (float)hv[1] * w0.y + (float)hv[2] * w0.z + (float)hv[3] * w0.w
                 + (float)hv[4] * w1.x + (float)hv[5] * w1.y + (float)hv[6] * w1.z + (float)hv[7] * w1.w;
        }
        sum += __shfl_down(sum, 2, 64);
        sum += __shfl_down(sum, 1, 64);
        if (part == 0) s_p[row * 2 + j] -= sum;
    }
    __syncthreads();

    float wc0[4], wc1[4], cg[4];
    #pragma unroll
    for (int g = 0; g < 4; ++g) {
        const int n = g * H + w * 16 + l15;
        wc0[g] = s_wc[n * 2];
        wc1[g] = s_wc[n * 2 + 1];
        cg[g]  = wc0[g] * s_bhp[0] + wc1[g] * s_bhp[1];
    }
    #pragma unroll
    for (int im = 0; im < 4; ++im)
        #pragma unroll
        for (int r = 0; r < 4; ++r) {
            const int mrow = im * 16 + q * 4 + r;
            const float pa = s_p[mrow * 2], pb = s_p[mrow * 2 + 1];
            #pragma unroll
            for (int g = 0; g < 4; ++g)
                gb[im][g][r] += pa * wc0[g] + pb * wc1[g];
        }

    for (int t = 0; t < SEQLEN; ++t) {
        f32x4 acc[4][4];
        #pragma unroll
        for (int kt = 0; kt < 4; ++kt) {
            f16x8 af[4];
            #pragma unroll
            for (int im = 0; im < 4; ++im)
                af[im] = *(const f16x8*)(s_h + (im * 16 + l15) * 136 + kt * 32 + q * 8);
            #pragma unroll
            for (int g = 0; g < 4; ++g) {
                const f16x8 bf = *(const f16x8*)(s_whh + (g * H + w * 16 + l15) * 136 + kt * 32 + q * 8);
                #pragma unroll
                for (int im = 0; im < 4; ++im)
                    acc[im][g] = __builtin_amdgcn_mfma_f32_16x16x32_f16(
                        af[im], bf, (kt == 0) ? gb[im][g] : acc[im][g], 0, 0, 0);
            }
        }
        __syncthreads();

        #pragma unroll
        for (int im = 0; im < 4; ++im) {
            #pragma unroll
            for (int r = 0; r < 4; ++r) {
                const int mrow = im * 16 + q * 4 + r;
                const float cc = sigf(acc[im][1][r]) * cst[im][r]
                               + sigf(acc[im][0][r]) * tanhfast(acc[im][2][r]);
                cst[im][r] = cc;
                const float hh = sigf(acc[im][3][r]) * tanhfast(cc);
                s_h[mrow * 136 + w * 16 + l15] = (_Float16)hh;
            }
        }
        if (t == 0) {
            #pragma unroll
            for (int im = 0; im < 4; ++im)
                #pragma unroll
                for (int r = 0; r < 4; ++r) {
                    const int mrow = im * 16 + q * 4 + r;
                    const float pa = s_p[mrow * 2], pb = s_p[mrow * 2 + 1];
                    #pragma unroll
                    for (int g = 0; g < 4; ++g)
                        gb[im][g][r] += cg[g] - (pa * wc0[g] + pb * wc1[g]);
                }
        }
        __syncthreads();

        {
            const int part = tid & 3;
            const int j    = (tid >> 2) & 1;
            const int row  = tid >> 3;
            float sum = 0.f;
            #pragma unroll
            for (int u = 0; u < 4; ++u) {
                const f16x8 hv = *(const f16x8*)(s_h + row * 136 + part * 32 + u * 8);
                const float4* wp = (const float4*)(s_whp + j * H + part * 32 + u * 8);
                const float4 w0 = wp[0], w1 = wp[1];
                sum += (float)hv[0] * w0.x + (float)hv[1] * w0.y + (float)hv[2] * w0.z + (float)hv[3] * w0.w
                     + (float)hv[4] * w1.x + (float)hv[5] * w1.y + (float)hv[6] * w1.z + (float)hv[7] * w1.w;
            }
            sum += __shfl_down(sum, 2, 64);
            sum += __shfl_down(sum, 1, 64);
            if (part == 0)
                out[(size_t)t * (BATCH * 2) + (size_t)(m0 + row) * 2 + j] = sum + s_bhp[j];
        }
    }
}

// ---------------------------------------------------------------------------
extern "C" void kernel_launch(void* const* d_in, const int* in_sizes, int n_in,
                              void* d_out, int out_size, void* d_ws, size_t ws_size,
                              hipStream_t stream)
{
    const float* last_pos_rel = (const float*)d_in[1];
    const float* enc          = (const float*)d_in[2];
    const float* zin          = (const float*)d_in[3];
    const float* W_ih         = (const float*)d_in[5];
    const float* W_hh         = (const float*)d_in[6];
    const float* b_ih         = (const float*)d_in[7];
    const float* b_hh         = (const float*)d_in[8];
    const float* W1           = (const float*)d_in[9];
    const float* b1           = (const float*)d_in[10];
    const float* W2           = (const float*)d_in[11];
    const float* b2           = (const float*)d_in[12];
    const float* W_sp         = (const float*)d_in[13];
    const float* b_sp         = (const float*)d_in[14];
    const float* W_hp         = (const float*)d_in[15];
    const float* b_hp         = (const float*)d_in[16];
    float* out = (float*)d_out;

    char* ws = (char*)d_ws;
    const bool big = (ws_size >= B_TOTAL);

    _Float16* wcat  = (_Float16*)(ws + (big ? B_WCAT_OFF  : S_WCAT_OFF));
    _Float16* w2h   = (_Float16*)(ws + (big ? B_W2H_OFF   : S_W2H_OFF));
    _Float16* whhf  = (_Float16*)(ws + (big ? B_WHHF_OFF  : S_WHHF_OFF));
    float*    wc    = (float*)(ws + (big ? B_WC_OFF    : S_WC_OFF));
    float*    bias2 = (float*)(ws + (big ? B_BIAS2_OFF : S_BIAS2_OFF));
    _Float16* t1    = (_Float16*)(ws + (big ? B_T1_OFF : S_T1_OFF));
    float*    gperm = (float*)(ws + (big ? B_GP_OFF : S_GP_OFF));
    _Float16* h0b   = (_Float16*)(ws + (big ? B_H0_OFF : S_H0_OFF));
    _Float16* zx16  = (_Float16*)(ws + B_ZX16_OFF);

    prep_kernel<<<dim3(1926), 256, 0, stream>>>(W_ih, W_hh, b_ih, b_hh, W1, W2, W_sp, b_sp,
                                                W_hp, big ? KP : ZX, wcat, w2h, whhf, wc, bias2);
    if (big) {
        zxcast_kernel<<<dim3(17408), 256, 0, stream>>>(enc, zin, zx16);
        gemm1_big_kernel<<<dim3(768), 512, 0, stream>>>(zx16, wcat, b1, bias2, t1, gperm);
    } else {
        gemm1_small_kernel<<<dim3(3072), 256, 0, stream>>>(enc, zin, wcat, b1, bias2, t1, gperm);
    }
    gemm2_kernel<<<dim3(512), 256, 0, stream>>>(t1, w2h, b2, h0b);
    recur_kernel<<<dim3(512), 512, 0, stream>>>(gperm, h0b, whhf, wc, W_hp, b_hp,
                                                last_pos_rel, out);
}